// Round 15
// baseline (126.098 us; speedup 1.0000x reference)
//
#include <hip/hip_runtime.h>
#include <hip/hip_bf16.h>
#include <stdint.h>

// B=8, N=1024, D=512, H=8, DK=64, ALPHA=0.2
//
// Scratch plan:
//   ws : [0..8.4MB) xb (attn out bf16); [8.4..8.9MB) wo16 IF ws_size >= 8,912,896.
//   d_out doubles as scratch (write-before-read, dead before final GEMM):
//     vt    @ 0          8,388,608  (v^T per head: [b][h][dk][n] bf16)
//     mbit  @ 8,388,608  1,048,576  (mask bitset, [b][i][128B])
//     sq    @ 9,437,184    262,144  ([b][h][n] f32, pre-scaled by log2e)
//     sk    @ 9,699,328    262,144
//     Bfrag @ 9,961,472     16,384  (bf16 MFMA B-frags for sqsk)
//     qkb   @ 9,977,856         64
//     wv16  @10,485,760    524,288  (Wv bf16)

typedef __attribute__((ext_vector_type(8))) short short8;
typedef __attribute__((ext_vector_type(4))) float f32x4;

#define LB __launch_bounds__(256)
#define LB512 __launch_bounds__(512)

union U8 { unsigned u[4]; short8 s; uint4 v; };
union U2 { unsigned u[2]; uint2 v; };

__device__ __forceinline__ unsigned short f2bf(float f) {
  unsigned int u = __float_as_uint(f);
  u += 0x7fffu + ((u >> 16) & 1u);
  return (unsigned short)(u >> 16);
}

// v_cvt_pk_bf16_f32: lo16 = bf16(a), hi16 = bf16(b), RNE (bit-identical to f2bf)
__device__ __forceinline__ unsigned cvt_pk(float a, float b) {
  unsigned r;
  asm("v_cvt_pk_bf16_f32 %0, %1, %2" : "=v"(r) : "v"(a), "v"(b));
  return r;
}

// async global->LDS, 16B per lane. lptr = wave-uniform base; gptr = per-lane.
__device__ __forceinline__ void async_cp16(const void* g, void* l) {
  __builtin_amdgcn_global_load_lds(
      (const __attribute__((address_space(1))) unsigned int*)g,
      (__attribute__((address_space(3))) unsigned int*)l, 16, 0, 0);
}

// ---------------- k1: weight casts + fold a into Wq/Wk -> Bfrag ----------------
__global__ LB void prep_kernel(const float* __restrict__ Wv, const float* __restrict__ Wo,
                               unsigned short* __restrict__ wv16, unsigned short* __restrict__ wo16,
                               const float* __restrict__ Wq, const float* __restrict__ Wk,
                               const float* __restrict__ a, const float* __restrict__ bq,
                               const float* __restrict__ bk,
                               unsigned short* __restrict__ Bfrag, float* __restrict__ qkb) {
  const int blk = blockIdx.x, tid = threadIdx.x;
  if (blk < 512) {
    const float* src = blk < 256 ? Wv : Wo;
    unsigned short* dst = blk < 256 ? wv16 : wo16;
    const int idx = ((blk & 255) * 256 + tid) * 4;
    const float4 v = *(const float4*)(src + idx);
    U2 pk;
    pk.u[0] = cvt_pk(v.x, v.y);
    pk.u[1] = cvt_pk(v.z, v.w);
    *(uint2*)(dst + idx) = pk.v;
    return;
  }
  const int t = (blk - 512) * 256 + tid;  // 4096 threads: d fast, h slow
  const int d = t & 511, h = t >> 9;
  float aq = 0.f, ak = 0.f;
#pragma unroll 4
  for (int dk = 0; dk < 64; ++dk) {
    aq += Wq[(size_t)(h * 64 + dk) * 512 + d] * a[h * 128 + dk];
    ak += Wk[(size_t)(h * 64 + dk) * 512 + d] * a[h * 128 + 64 + dk];
  }
  const float L2E = 1.4426950408889634f;
  const int ks = d >> 5, lch = (d >> 3) & 3, tt = d & 7;
  Bfrag[((ks * 64 + (lch << 4) + h) << 3) + tt] = f2bf(aq * L2E);
  Bfrag[((ks * 64 + (lch << 4) + 8 + h) << 3) + tt] = f2bf(ak * L2E);
  if (d == 0) {
    float s1 = 0.f, s2 = 0.f;
    for (int dk = 0; dk < 64; ++dk) {
      s1 += bq[h * 64 + dk] * a[h * 128 + dk];
      s2 += bk[h * 64 + dk] * a[h * 128 + 64 + dk];
    }
    qkb[h] = s1 * L2E;
    qkb[8 + h] = s2 * L2E;
  }
}

// ---------------- k2: gemm_v (0-1023) | sqsk (1024-1535) | maskbits (1536-9727) ------
__global__ LB void mid_kernel(const float* __restrict__ query, const float* __restrict__ key,
                              const unsigned short* __restrict__ Bfrag,
                              const float* __restrict__ qkb,
                              float* __restrict__ sq, float* __restrict__ sk,
                              const float* __restrict__ value,
                              const unsigned short* __restrict__ wv16,
                              const float* __restrict__ bvb, unsigned short* __restrict__ vt,
                              const int* __restrict__ mask, unsigned int* __restrict__ bits) {
  __shared__ char sm[20480];
  const int tid = threadIdx.x, w = tid >> 6, l = tid & 63;
  const int lr = l & 15, lc = l >> 4;
  const int bid = blockIdx.x;
  if (bid >= 1536) {
    // ---------- maskbits: int4 load + nibble pack via LDS ----------
    unsigned char* nb = (unsigned char*)sm;
    const size_t e0 = ((size_t)(bid - 1536) * 256 + tid) * 4;
    const int4 m = *(const int4*)(mask + e0);
    nb[tid] = (unsigned char)((m.x != 0) | ((m.y != 0) << 1) | ((m.z != 0) << 2) | ((m.w != 0) << 3));
    __syncthreads();
    if (tid < 32) {
      const uint2 p = *(const uint2*)(nb + tid * 8);
      const unsigned lo = p.x, hi = p.y;
      const unsigned wl = (lo & 0xFu) | ((lo >> 4) & 0xF0u) | ((lo >> 8) & 0xF00u) | ((lo >> 12) & 0xF000u);
      const unsigned wh = (hi & 0xFu) | ((hi >> 4) & 0xF0u) | ((hi >> 8) & 0xF00u) | ((hi >> 12) & 0xF000u);
      bits[(bid - 1536) * 32 + tid] = wl | (wh << 16);
    }
    return;
  }
  if (bid >= 1024) {
    // ---------- sqsk: rank-16 MFMA skinny GEMM ----------
    float* comb = (float*)sm;
    const int m0 = (bid - 1024) * 16;
    const int k0 = w * 128;
    short8 bf[4];
#pragma unroll
    for (int ks = 0; ks < 4; ++ks)
      bf[ks] = *(const short8*)(Bfrag + (((w * 4 + ks) * 64 + l) << 3));
    const float* qbase = query + (size_t)(m0 + lr) * 512 + k0 + (lc << 3);
    const float* kbase = key + (size_t)(m0 + lr) * 512 + k0 + (lc << 3);
    f32x4 cq = {}, ck = {};
#pragma unroll
    for (int ks = 0; ks < 4; ++ks) {
      const float4 q0 = *(const float4*)(qbase + ks * 32);
      const float4 q1 = *(const float4*)(qbase + ks * 32 + 4);
      const float4 k0v = *(const float4*)(kbase + ks * 32);
      const float4 k1v = *(const float4*)(kbase + ks * 32 + 4);
      U8 aq, ak;
      aq.u[0] = cvt_pk(q0.x, q0.y); aq.u[1] = cvt_pk(q0.z, q0.w);
      aq.u[2] = cvt_pk(q1.x, q1.y); aq.u[3] = cvt_pk(q1.z, q1.w);
      ak.u[0] = cvt_pk(k0v.x, k0v.y); ak.u[1] = cvt_pk(k0v.z, k0v.w);
      ak.u[2] = cvt_pk(k1v.x, k1v.y); ak.u[3] = cvt_pk(k1v.z, k1v.w);
      cq = __builtin_amdgcn_mfma_f32_16x16x32_bf16(aq.s, bf[ks], cq, 0, 0, 0);
      ck = __builtin_amdgcn_mfma_f32_16x16x32_bf16(ak.s, bf[ks], ck, 0, 0, 0);
    }
    if (w) {
      float* p = comb + ((w - 1) * 64 + l) * 9;
#pragma unroll
      for (int r = 0; r < 4; ++r) { p[r] = cq[r]; p[4 + r] = ck[r]; }
    }
    __syncthreads();
    if (w == 0) {
#pragma unroll
      for (int j = 0; j < 3; ++j) {
        const float* p = comb + (j * 64 + l) * 9;
#pragma unroll
        for (int r = 0; r < 4; ++r) { cq[r] += p[r]; ck[r] += p[4 + r]; }
      }
      const int col = l & 15;
      const int mbase = m0 + (lc << 2);
      const int b = mbase >> 10;
      const float bia = qkb[col];
      if (col < 8) {
        float* out = sq + ((size_t)b * 8 + col) * 1024;
#pragma unroll
        for (int r = 0; r < 4; ++r) out[(mbase + r) & 1023] = cq[r] + bia;
      } else {
        float* out = sk + ((size_t)b * 8 + (col - 8)) * 1024;
#pragma unroll
        for (int r = 0; r < 4; ++r) out[(mbase + r) & 1023] = ck[r] + bia;
      }
    }
    return;
  }
  // ---------- gemm_v: vt = value @ Wv^T, A f32 reg-staged, dbuf counted-vmcnt ----------
  unsigned short* As = (unsigned short*)sm;
  unsigned short* Bs = (unsigned short*)(sm + 4096);
  const int bm = bid >> 2, bn = bid & 3;
  const int m0 = bm * 32, n0 = bn * 128;
  const int wr = (w & 1) * 16, wc = (w >> 1) * 64;
  const int rch = (lc ^ ((lr >> 1) & 3)) << 3;
  const int arow = (w << 3) + (l >> 3);
  const int akc = l & 7;
  const float* asrc = value + (size_t)(m0 + arow) * 512 + (akc << 2);
  const int ach = ((akc >> 1) ^ ((arow >> 1) & 3));
  const int aoff = arow * 32 + (ach << 3) + ((akc & 1) << 2);
  const int crow = l >> 2;
  const int brow0 = (w << 4) + crow, brow1 = ((w + 4) << 4) + crow;
  const unsigned short* bsrc0 = wv16 + (size_t)(n0 + brow0) * 512 + (((l & 3) ^ ((brow0 >> 1) & 3)) << 3);
  const unsigned short* bsrc1 = wv16 + (size_t)(n0 + brow1) * 512 + (((l & 3) ^ ((brow1 >> 1) & 3)) << 3);

  f32x4 acc[4] = {};
  float4 areg = *(const float4*)(asrc);
  async_cp16(bsrc0, Bs + (w << 9));
  async_cp16(bsrc1, Bs + ((w + 4) << 9));
  {
    U2 aw;
    aw.u[0] = cvt_pk(areg.x, areg.y);
    aw.u[1] = cvt_pk(areg.z, areg.w);
    *(uint2*)(As + aoff) = aw.v;
  }
  areg = *(const float4*)(asrc + 32);
  async_cp16(bsrc0 + 32, Bs + 4096 + (w << 9));
  async_cp16(bsrc1 + 32, Bs + 4096 + ((w + 4) << 9));
  asm volatile("s_waitcnt vmcnt(3)" ::: "memory");
  asm volatile("s_waitcnt lgkmcnt(0)" ::: "memory");
  __builtin_amdgcn_sched_barrier(0);
  __builtin_amdgcn_s_barrier();
  int buf = 0;
  for (int kt = 0; kt < 16; ++kt) {
    const short8 af = *(const short8*)(As + (buf << 10) + (wr + lr) * 32 + rch);
    __builtin_amdgcn_s_setprio(1);
#pragma unroll
    for (int j = 0; j < 4; ++j) {
      const short8 bfr = *(const short8*)(Bs + (buf << 12) + (wc + j * 16 + lr) * 32 + rch);
      acc[j] = __builtin_amdgcn_mfma_f32_16x16x32_bf16(af, bfr, acc[j], 0, 0, 0);
    }
    __builtin_amdgcn_s_setprio(0);
    __builtin_amdgcn_s_barrier();
    if (kt < 15) {
      U2 aw;
      aw.u[0] = cvt_pk(areg.x, areg.y);
      aw.u[1] = cvt_pk(areg.z, areg.w);
      *(uint2*)(As + ((buf ^ 1) << 10) + aoff) = aw.v;
      if (kt < 14) {
        areg = *(const float4*)(asrc + (kt + 2) * 32);
        async_cp16(bsrc0 + (kt + 2) * 32, Bs + (buf << 12) + (w << 9));
        async_cp16(bsrc1 + (kt + 2) * 32, Bs + (buf << 12) + ((w + 4) << 9));
        asm volatile("s_waitcnt vmcnt(3)" ::: "memory");
      } else {
        asm volatile("s_waitcnt vmcnt(0)" ::: "memory");
      }
      asm volatile("s_waitcnt lgkmcnt(0)" ::: "memory");
      __builtin_amdgcn_sched_barrier(0);
      __builtin_amdgcn_s_barrier();
    }
    buf ^= 1;
  }
#pragma unroll
  for (int j = 0; j < 4; ++j) {
    const int nn = n0 + wc + j * 16 + lr;
    const float bia = bvb[nn];
    const int mm0 = m0 + wr + lc * 4;
    const int b = mm0 >> 10, t0 = mm0 & 1023;
    const int h = nn >> 6, dk = nn & 63;
    U2 pk;
    pk.u[0] = cvt_pk(acc[j][0] + bia, acc[j][1] + bia);
    pk.u[1] = cvt_pk(acc[j][2] + bia, acc[j][3] + bia);
    *(uint2*)(vt + (((size_t)((b * 8 + h) * 64 + dk)) << 10) + t0) = pk.v;
  }
}

// ---------------- k4: bf16 MFMA GEMM (gemm_o) ----------------
template <int BB16>
__global__ LB void gemm_bt(const unsigned short* __restrict__ A,
                           const void* __restrict__ Bwp,
                           const float* __restrict__ bias, float* __restrict__ outp) {
  __shared__ unsigned short As[2][32 * 32];
  __shared__ unsigned short Bs[2][128 * 32];
  const int tid = threadIdx.x;
  const int w = tid >> 6, l = tid & 63;
  const int lr = l & 15, lc = l >> 4;
  const int bm = blockIdx.x >> 2, bn = blockIdx.x & 3;
  const int m0 = bm * 32, n0 = bn * 128;
  const int wr = (w & 1) * 16, wc = (w >> 1) * 64;
  const int rch = (lc ^ ((lr >> 1) & 3)) << 3;
  const int arow = (w << 3) + (l >> 2);
  const int asc = (l & 3) ^ ((arow >> 1) & 3);
  const unsigned short* asrc = A + (size_t)(m0 + arow) * 512 + (asc << 3);
  const int crow = l >> 2;
  const unsigned short* b16 = (const unsigned short*)Bwp;
  const float* b32 = (const float*)Bwp;
  const int brow0 = (w << 4) + crow, brow1 = ((w + 4) << 4) + crow;
  const unsigned short* bsrc0 = b16 + (size_t)(n0 + brow0) * 512 + (((l & 3) ^ ((brow0 >> 1) & 3)) << 3);
  const unsigned short* bsrc1 = b16 + (size_t)(n0 + brow1) * 512 + (((l & 3) ^ ((brow1 >> 1) & 3)) << 3);

  f32x4 acc[4] = {};
  if (BB16) {
    if (l < 32) async_cp16(asrc, As[0] + (w << 8));
    async_cp16(bsrc0, Bs[0] + (w << 9));
    async_cp16(bsrc1, Bs[0] + ((w + 4) << 9));
    int buf = 0;
    for (int kt = 0; kt < 16; ++kt) {
      if (kt < 15) {
        const int k1 = (kt + 1) * 32;
        if (l < 32) async_cp16(asrc + k1, As[buf ^ 1] + (w << 8));
        async_cp16(bsrc0 + k1, Bs[buf ^ 1] + (w << 9));
        async_cp16(bsrc1 + k1, Bs[buf ^ 1] + ((w + 4) << 9));
        asm volatile("s_waitcnt vmcnt(3)" ::: "memory");
      } else {
        asm volatile("s_waitcnt vmcnt(0)" ::: "memory");
      }
      __builtin_amdgcn_sched_barrier(0);
      __builtin_amdgcn_s_barrier();
      const short8 af = *(const short8*)(As[buf] + (wr + lr) * 32 + rch);
      __builtin_amdgcn_s_setprio(1);
#pragma unroll
      for (int j = 0; j < 4; ++j) {
        const short8 bfr = *(const short8*)(Bs[buf] + (wc + j * 16 + lr) * 32 + rch);
        acc[j] = __builtin_amdgcn_mfma_f32_16x16x32_bf16(af, bfr, acc[j], 0, 0, 0);
      }
      __builtin_amdgcn_s_setprio(0);
      if (kt < 15) __builtin_amdgcn_s_barrier();
      buf ^= 1;
    }
  } else {
    for (int kt = 0; kt < 16; ++kt) {
      const int k0 = kt * 32;
      if (kt) __syncthreads();
      if (l < 32) async_cp16(asrc + k0, As[0] + (w << 8));
#pragma unroll
      for (int it = 0; it < 2; ++it) {
        const int idx = it * 256 + tid;
        const int row = idx >> 2, gr = idx & 3;
        const int sch = (gr ^ ((row >> 1) & 3)) << 3;
        const float4* src = (const float4*)(b32 + (size_t)(n0 + row) * 512 + k0 + gr * 8);
        const float4 b0 = src[0], b1 = src[1];
        U8 t8;
        t8.u[0] = cvt_pk(b0.x, b0.y); t8.u[1] = cvt_pk(b0.z, b0.w);
        t8.u[2] = cvt_pk(b1.x, b1.y); t8.u[3] = cvt_pk(b1.z, b1.w);
        *(uint4*)(Bs[0] + row * 32 + sch) = t8.v;
      }
      __syncthreads();
      const short8 af = *(const short8*)(As[0] + (wr + lr) * 32 + rch);
#pragma unroll
      for (int j = 0; j < 4; ++j) {
        const short8 bfr = *(const short8*)(Bs[0] + (wc + j * 16 + lr) * 32 + rch);
        acc[j] = __builtin_amdgcn_mfma_f32_16x16x32_bf16(af, bfr, acc[j], 0, 0, 0);
      }
    }
  }
#pragma unroll
  for (int j = 0; j < 4; ++j) {
    const int nn = n0 + wc + j * 16 + lr;
    const float bia = bias[nn];
    const int mm0 = m0 + wr + lc * 4;
#pragma unroll
    for (int r = 0; r < 4; ++r)
      outp[(size_t)(mm0 + r) * 512 + nn] = acc[j][r] + bia;
  }
}

// ---------------- k3: fused attention, register-resident V, PROVEN orientation -------
// Grid 1024 x 512thr (bh = bid&63 XCD affinity, iblk = bid>>6 -> 64 rows). 8 waves =
// 8 j-eighths (128 j, 4 k-steps). pa built EXACTLY as R12 (proven); V^T fragments for
// the wave's j-slice preloaded to registers with the same per-lane content R12's LDS
// reads produced (chunk = lc, swizzle cancels). Main loop: zero LDS staging, zero
// barriers, zero vmcnt. Epilogue: serial 8-way combine via one pad-81 LDS buffer.
__global__ LB512 void attn_kernel(const float* __restrict__ sq, const float* __restrict__ sk,
                                  const unsigned char* __restrict__ mbits,
                                  const unsigned short* __restrict__ vt,
                                  unsigned short* __restrict__ xb) {
  __shared__ char smem[21504];
  float* sks = (float*)smem;            // [1024] f32 (4KB)
  char* mks = smem + 4096;              // [64 rows][128B], byte-swizzled (8KB)
  // cmb overlays smem after the main loop: [64][81] f32 = 20,736 B
  const int tid = threadIdx.x;
  const int w = tid >> 6, l = tid & 63;
  const int lr = l & 15, lc = l >> 4;
  const int bid = blockIdx.x;
  const int bh = bid & 63, iblk = bid >> 6;
  const int b = bh >> 3, h = bh & 7;
  const int i0b = iblk << 6;   // 64 rows per block
  const int j0 = w << 7;       // 128 j per wave
  const float* sqp = sq + (size_t)bh * 1024;
  const float* skp = sk + (size_t)bh * 1024;
  const unsigned short* vtp = vt + ((size_t)bh << 16);
  const unsigned char* mrow = mbits + ((size_t)b << 17);

  // ---- prologue: stage sks + mks (async), preload V^T frags + sq to registers
  if (w < 4) async_cp16(skp + (w << 8) + l * 4, sks + (w << 8));
  {
    const int row = (w << 3) + (l >> 3);
    const int c = (l & 7) ^ (row & 7);
    async_cp16(mrow + (size_t)(i0b + row) * 128 + (c << 4), mks + (w << 10));
  }
  // B-operand frags: lane holds V^T[dk = c*16 + lr][j = j0 + s*32 + lc*8 .. +7]
  // (identical content to R12's LDS bv after its swizzle cancellation)
  short8 vrb[4][4];
#pragma unroll
  for (int c = 0; c < 4; ++c)
#pragma unroll
    for (int s = 0; s < 4; ++s)
      vrb[c][s] = *(const short8*)(vtp + (size_t)(c * 16 + lr) * 1024 + j0 + s * 32 + (lc << 3));
  float sq8[4];
#pragma unroll
  for (int t = 0; t < 4; ++t) sq8[t] = sqp[i0b + (t << 4) + lr];
  __syncthreads();

  f32x4 acc[4][4] = {};   // [t: i-tile][c: dk-tile]
  f32x4 accs[4] = {};     // rowsums
  short8 ones;
#pragma unroll
  for (int t = 0; t < 8; ++t) ones[t] = (short)0x3f80;  // bf16 1.0
  const int rx = (lr & 7) << 4;

#pragma unroll
  for (int s = 0; s < 4; ++s) {
    const int jb = j0 + (s << 5);
    const int qb = (jb >> 3) + lc;
    const f32x4 s0 = *(const f32x4*)(sks + jb + (lc << 3));
    const f32x4 s1 = *(const f32x4*)(sks + jb + (lc << 3) + 4);
    U8 pa[4];
#pragma unroll
    for (int t = 0; t < 4; ++t) {
      const int row = (t << 4) + lr;
      const unsigned mb = (unsigned char)mks[(row << 7) + (qb ^ rx)];
      const float sqv = sq8[t];
      float e[8];
#pragma unroll
      for (int u = 0; u < 8; ++u) {
        float sv = sqv + (u < 4 ? s0[u] : s1[u - 4]);
        sv = fmaxf(sv, 0.2f * sv);  // leaky relu (log2e pre-folded)
        const float ex = __builtin_amdgcn_exp2f(sv);
        e[u] = (mb & (1u << u)) ? ex : 0.0f;
      }
      pa[t].u[0] = cvt_pk(e[0], e[1]); pa[t].u[1] = cvt_pk(e[2], e[3]);
      pa[t].u[2] = cvt_pk(e[4], e[5]); pa[t].u[3] = cvt_pk(e[6], e[7]);
    }
    __builtin_amdgcn_s_setprio(1);
#pragma unroll
    for (int c = 0; c < 4; ++c)
#pragma unroll
      for (int t = 0; t < 4; ++t)
        acc[t][c] = __builtin_amdgcn_mfma_f32_16x16x32_bf16(pa[t].s, vrb[c][s], acc[t][c], 0, 0, 0);
#pragma unroll
    for (int t = 0; t < 4; ++t)
      accs[t] = __builtin_amdgcn_mfma_f32_16x16x32_bf16(pa[t].s, ones, accs[t], 0, 0, 0);
    __builtin_amdgcn_s_setprio(0);
  }

  // ---- serial 8-way j-combine through one pad-81 buffer (overlays dead sks/mks)
  float* cmb = (float*)smem;  // [64][81] f32
  __syncthreads();
#pragma unroll 1
  for (int src = 1; src < 8; ++src) {
    if (w == src) {
      float* p = cmb + l * 81;
#pragma unroll
      for (int t = 0; t < 4; ++t) {
#pragma unroll
        for (int c = 0; c < 4; ++c) *(f32x4*)(p + (t * 4 + c) * 4) = acc[t][c];
        *(f32x4*)(p + 64 + t * 4) = accs[t];
      }
    }
    __syncthreads();
    if (w == 0) {
      const float* p = cmb + l * 81;
#pragma unroll
      for (int t = 0; t < 4; ++t) {
#pragma unroll
        for (int c = 0; c < 4; ++c) {
          const f32x4 v = *(const f32x4*)(p + (t * 4 + c) * 4);
#pragma unroll
          for (int r = 0; r < 4; ++r) acc[t][c][r] += v[r];
        }
        const f32x4 vs = *(const f32x4*)(p + 64 + t * 4);
#pragma unroll
        for (int r = 0; r < 4; ++r) accs[t][r] += vs[r];
      }
    }
    __syncthreads();
  }
  if (w == 0) {
#pragma unroll
    for (int t = 0; t < 4; ++t) {
#pragma unroll
      for (int r = 0; r < 4; ++r) {
        const float sv = accs[t][r];
        const float inv = sv > 0.0f ? 1.0f / sv : 0.0f;  // fully-masked row -> 0
        const int i = i0b + (t << 4) + (lc << 2) + r;
#pragma unroll
        for (int c = 0; c < 4; ++c)
          xb[(((size_t)(b * 1024 + i)) << 9) + h * 64 + (c << 4) + lr] =
              f2bf(acc[t][c][r] * inv);
      }
    }
  }
}

extern "C" void kernel_launch(void* const* d_in, const int* in_sizes, int n_in,
                              void* d_out, int out_size, void* d_ws, size_t ws_size,
                              hipStream_t stream) {
  const float* query = (const float*)d_in[0];
  const float* key   = (const float*)d_in[1];
  const float* value = (const float*)d_in[2];
  const int*   mask  = (const int*)d_in[3];
  const float* Wq = (const float*)d_in[4];
  const float* bq = (const float*)d_in[5];
  const float* Wk = (const float*)d_in[6];
  const float* bk = (const float*)d_in[7];
  const float* Wv = (const float*)d_in[8];
  const float* bv = (const float*)d_in[9];
  const float* Wo = (const float*)d_in[10];
  const float* bo = (const float*)d_in[11];
  const float* a  = (const float*)d_in[12];

  char* oc = (char*)d_out;
  unsigned short* vt = (unsigned short*)(oc + 0);
  unsigned int* mbits = (unsigned int*)(oc + 8388608);
  float* sqv = (float*)(oc + 9437184);
  float* skv = (float*)(oc + 9699328);
  unsigned short* Bfrag = (unsigned short*)(oc + 9961472);
  float* qkb = (float*)(oc + 9977856);
  unsigned short* wv16 = (unsigned short*)(oc + 10485760);
  unsigned short* xb = (unsigned short*)d_ws;

  const bool roomy = ws_size >= 8912896;
  unsigned short* wo16 = roomy ? (unsigned short*)((char*)d_ws + 8388608) : (unsigned short*)(oc + 11010048);

  prep_kernel<<<528, 256, 0, stream>>>(Wv, Wo, wv16, wo16, Wq, Wk, a, bq, bk, Bfrag, qkb);
  mid_kernel<<<9728, 256, 0, stream>>>(query, key, Bfrag, qkb, sqv, skv,
                                       value, wv16, bv, vt, mask, mbits);
  attn_kernel<<<1024, 512, 0, stream>>>(sqv, skv, (const unsigned char*)mbits, vt, xb);
  if (roomy)
    gemm_bt<1><<<1024, 256, 0, stream>>>(xb, (const void*)wo16, bo, (float*)d_out);
  else
    gemm_bt<0><<<1024, 256, 0, stream>>>(xb, (const void*)Wo, bo, (float*)d_out);
}

// Round 17
// 125.282 us; speedup vs baseline: 1.0065x; 1.0065x over previous
//
#include <hip/hip_runtime.h>
#include <hip/hip_bf16.h>
#include <stdint.h>

// B=8, N=1024, D=512, H=8, DK=64, ALPHA=0.2
//
// Scratch plan:
//   ws : [0..8.4MB) xb (attn out bf16); [8.4..8.9MB) wo16 IF ws_size >= 8,912,896.
//   d_out doubles as scratch (write-before-read, dead before final GEMM):
//     vt    @ 0          8,388,608  (v^T per head: [b][h][dk][n] bf16)
//     mbit  @ 8,388,608  1,048,576  (mask bitset, [b][i][128B])
//     sq    @ 9,437,184    262,144  ([b][h][n] f32, pre-scaled by log2e)
//     sk    @ 9,699,328    262,144
//     Bfrag @ 9,961,472     16,384  (bf16 MFMA B-frags for sqsk)
//     qkb   @ 9,977,856         64
//     wv16  @10,485,760    524,288  (Wv bf16)

typedef __attribute__((ext_vector_type(8))) short short8;
typedef __attribute__((ext_vector_type(4))) float f32x4;

#define LB __launch_bounds__(256)
// 8-wave blocks = 2 waves/EU: declare it so the VGPR cap is ~256 and the
// register-resident V fragments actually stay in registers (R15: cap 88 -> sunk loads).
#define LB512 __launch_bounds__(512, 2)

union U8 { unsigned u[4]; short8 s; uint4 v; };
union U2 { unsigned u[2]; uint2 v; };

__device__ __forceinline__ unsigned short f2bf(float f) {
  unsigned int u = __float_as_uint(f);
  u += 0x7fffu + ((u >> 16) & 1u);
  return (unsigned short)(u >> 16);
}

// v_cvt_pk_bf16_f32: lo16 = bf16(a), hi16 = bf16(b), RNE (bit-identical to f2bf)
__device__ __forceinline__ unsigned cvt_pk(float a, float b) {
  unsigned r;
  asm("v_cvt_pk_bf16_f32 %0, %1, %2" : "=v"(r) : "v"(a), "v"(b));
  return r;
}

// async global->LDS, 16B per lane. lptr = wave-uniform base; gptr = per-lane.
__device__ __forceinline__ void async_cp16(const void* g, void* l) {
  __builtin_amdgcn_global_load_lds(
      (const __attribute__((address_space(1))) unsigned int*)g,
      (__attribute__((address_space(3))) unsigned int*)l, 16, 0, 0);
}

// ---------------- k1: weight casts + fold a into Wq/Wk -> Bfrag ----------------
__global__ LB void prep_kernel(const float* __restrict__ Wv, const float* __restrict__ Wo,
                               unsigned short* __restrict__ wv16, unsigned short* __restrict__ wo16,
                               const float* __restrict__ Wq, const float* __restrict__ Wk,
                               const float* __restrict__ a, const float* __restrict__ bq,
                               const float* __restrict__ bk,
                               unsigned short* __restrict__ Bfrag, float* __restrict__ qkb) {
  const int blk = blockIdx.x, tid = threadIdx.x;
  if (blk < 512) {
    const float* src = blk < 256 ? Wv : Wo;
    unsigned short* dst = blk < 256 ? wv16 : wo16;
    const int idx = ((blk & 255) * 256 + tid) * 4;
    const float4 v = *(const float4*)(src + idx);
    U2 pk;
    pk.u[0] = cvt_pk(v.x, v.y);
    pk.u[1] = cvt_pk(v.z, v.w);
    *(uint2*)(dst + idx) = pk.v;
    return;
  }
  const int t = (blk - 512) * 256 + tid;  // 4096 threads: d fast, h slow
  const int d = t & 511, h = t >> 9;
  float aq = 0.f, ak = 0.f;
#pragma unroll 4
  for (int dk = 0; dk < 64; ++dk) {
    aq += Wq[(size_t)(h * 64 + dk) * 512 + d] * a[h * 128 + dk];
    ak += Wk[(size_t)(h * 64 + dk) * 512 + d] * a[h * 128 + 64 + dk];
  }
  const float L2E = 1.4426950408889634f;
  const int ks = d >> 5, lch = (d >> 3) & 3, tt = d & 7;
  Bfrag[((ks * 64 + (lch << 4) + h) << 3) + tt] = f2bf(aq * L2E);
  Bfrag[((ks * 64 + (lch << 4) + 8 + h) << 3) + tt] = f2bf(ak * L2E);
  if (d == 0) {
    float s1 = 0.f, s2 = 0.f;
    for (int dk = 0; dk < 64; ++dk) {
      s1 += bq[h * 64 + dk] * a[h * 128 + dk];
      s2 += bk[h * 64 + dk] * a[h * 128 + 64 + dk];
    }
    qkb[h] = s1 * L2E;
    qkb[8 + h] = s2 * L2E;
  }
}

// ---------------- k2: gemm_v (0-1023) | sqsk (1024-1535) | maskbits (1536-9727) ------
__global__ LB void mid_kernel(const float* __restrict__ query, const float* __restrict__ key,
                              const unsigned short* __restrict__ Bfrag,
                              const float* __restrict__ qkb,
                              float* __restrict__ sq, float* __restrict__ sk,
                              const float* __restrict__ value,
                              const unsigned short* __restrict__ wv16,
                              const float* __restrict__ bvb, unsigned short* __restrict__ vt,
                              const int* __restrict__ mask, unsigned int* __restrict__ bits) {
  __shared__ char sm[20480];
  const int tid = threadIdx.x, w = tid >> 6, l = tid & 63;
  const int lr = l & 15, lc = l >> 4;
  const int bid = blockIdx.x;
  if (bid >= 1536) {
    // ---------- maskbits: int4 load + nibble pack via LDS ----------
    unsigned char* nb = (unsigned char*)sm;
    const size_t e0 = ((size_t)(bid - 1536) * 256 + tid) * 4;
    const int4 m = *(const int4*)(mask + e0);
    nb[tid] = (unsigned char)((m.x != 0) | ((m.y != 0) << 1) | ((m.z != 0) << 2) | ((m.w != 0) << 3));
    __syncthreads();
    if (tid < 32) {
      const uint2 p = *(const uint2*)(nb + tid * 8);
      const unsigned lo = p.x, hi = p.y;
      const unsigned wl = (lo & 0xFu) | ((lo >> 4) & 0xF0u) | ((lo >> 8) & 0xF00u) | ((lo >> 12) & 0xF000u);
      const unsigned wh = (hi & 0xFu) | ((hi >> 4) & 0xF0u) | ((hi >> 8) & 0xF00u) | ((hi >> 12) & 0xF000u);
      bits[(bid - 1536) * 32 + tid] = wl | (wh << 16);
    }
    return;
  }
  if (bid >= 1024) {
    // ---------- sqsk: rank-16 MFMA skinny GEMM ----------
    float* comb = (float*)sm;
    const int m0 = (bid - 1024) * 16;
    const int k0 = w * 128;
    short8 bf[4];
#pragma unroll
    for (int ks = 0; ks < 4; ++ks)
      bf[ks] = *(const short8*)(Bfrag + (((w * 4 + ks) * 64 + l) << 3));
    const float* qbase = query + (size_t)(m0 + lr) * 512 + k0 + (lc << 3);
    const float* kbase = key + (size_t)(m0 + lr) * 512 + k0 + (lc << 3);
    f32x4 cq = {}, ck = {};
#pragma unroll
    for (int ks = 0; ks < 4; ++ks) {
      const float4 q0 = *(const float4*)(qbase + ks * 32);
      const float4 q1 = *(const float4*)(qbase + ks * 32 + 4);
      const float4 k0v = *(const float4*)(kbase + ks * 32);
      const float4 k1v = *(const float4*)(kbase + ks * 32 + 4);
      U8 aq, ak;
      aq.u[0] = cvt_pk(q0.x, q0.y); aq.u[1] = cvt_pk(q0.z, q0.w);
      aq.u[2] = cvt_pk(q1.x, q1.y); aq.u[3] = cvt_pk(q1.z, q1.w);
      ak.u[0] = cvt_pk(k0v.x, k0v.y); ak.u[1] = cvt_pk(k0v.z, k0v.w);
      ak.u[2] = cvt_pk(k1v.x, k1v.y); ak.u[3] = cvt_pk(k1v.z, k1v.w);
      cq = __builtin_amdgcn_mfma_f32_16x16x32_bf16(aq.s, bf[ks], cq, 0, 0, 0);
      ck = __builtin_amdgcn_mfma_f32_16x16x32_bf16(ak.s, bf[ks], ck, 0, 0, 0);
    }
    if (w) {
      float* p = comb + ((w - 1) * 64 + l) * 9;
#pragma unroll
      for (int r = 0; r < 4; ++r) { p[r] = cq[r]; p[4 + r] = ck[r]; }
    }
    __syncthreads();
    if (w == 0) {
#pragma unroll
      for (int j = 0; j < 3; ++j) {
        const float* p = comb + (j * 64 + l) * 9;
#pragma unroll
        for (int r = 0; r < 4; ++r) { cq[r] += p[r]; ck[r] += p[4 + r]; }
      }
      const int col = l & 15;
      const int mbase = m0 + (lc << 2);
      const int b = mbase >> 10;
      const float bia = qkb[col];
      if (col < 8) {
        float* out = sq + ((size_t)b * 8 + col) * 1024;
#pragma unroll
        for (int r = 0; r < 4; ++r) out[(mbase + r) & 1023] = cq[r] + bia;
      } else {
        float* out = sk + ((size_t)b * 8 + (col - 8)) * 1024;
#pragma unroll
        for (int r = 0; r < 4; ++r) out[(mbase + r) & 1023] = ck[r] + bia;
      }
    }
    return;
  }
  // ---------- gemm_v: vt = value @ Wv^T, A f32 reg-staged, dbuf counted-vmcnt ----------
  unsigned short* As = (unsigned short*)sm;
  unsigned short* Bs = (unsigned short*)(sm + 4096);
  const int bm = bid >> 2, bn = bid & 3;
  const int m0 = bm * 32, n0 = bn * 128;
  const int wr = (w & 1) * 16, wc = (w >> 1) * 64;
  const int rch = (lc ^ ((lr >> 1) & 3)) << 3;
  const int arow = (w << 3) + (l >> 3);
  const int akc = l & 7;
  const float* asrc = value + (size_t)(m0 + arow) * 512 + (akc << 2);
  const int ach = ((akc >> 1) ^ ((arow >> 1) & 3));
  const int aoff = arow * 32 + (ach << 3) + ((akc & 1) << 2);
  const int crow = l >> 2;
  const int brow0 = (w << 4) + crow, brow1 = ((w + 4) << 4) + crow;
  const unsigned short* bsrc0 = wv16 + (size_t)(n0 + brow0) * 512 + (((l & 3) ^ ((brow0 >> 1) & 3)) << 3);
  const unsigned short* bsrc1 = wv16 + (size_t)(n0 + brow1) * 512 + (((l & 3) ^ ((brow1 >> 1) & 3)) << 3);

  f32x4 acc[4] = {};
  float4 areg = *(const float4*)(asrc);
  async_cp16(bsrc0, Bs + (w << 9));
  async_cp16(bsrc1, Bs + ((w + 4) << 9));
  {
    U2 aw;
    aw.u[0] = cvt_pk(areg.x, areg.y);
    aw.u[1] = cvt_pk(areg.z, areg.w);
    *(uint2*)(As + aoff) = aw.v;
  }
  areg = *(const float4*)(asrc + 32);
  async_cp16(bsrc0 + 32, Bs + 4096 + (w << 9));
  async_cp16(bsrc1 + 32, Bs + 4096 + ((w + 4) << 9));
  asm volatile("s_waitcnt vmcnt(3)" ::: "memory");
  asm volatile("s_waitcnt lgkmcnt(0)" ::: "memory");
  __builtin_amdgcn_sched_barrier(0);
  __builtin_amdgcn_s_barrier();
  int buf = 0;
  for (int kt = 0; kt < 16; ++kt) {
    const short8 af = *(const short8*)(As + (buf << 10) + (wr + lr) * 32 + rch);
    __builtin_amdgcn_s_setprio(1);
#pragma unroll
    for (int j = 0; j < 4; ++j) {
      const short8 bfr = *(const short8*)(Bs + (buf << 12) + (wc + j * 16 + lr) * 32 + rch);
      acc[j] = __builtin_amdgcn_mfma_f32_16x16x32_bf16(af, bfr, acc[j], 0, 0, 0);
    }
    __builtin_amdgcn_s_setprio(0);
    __builtin_amdgcn_s_barrier();
    if (kt < 15) {
      U2 aw;
      aw.u[0] = cvt_pk(areg.x, areg.y);
      aw.u[1] = cvt_pk(areg.z, areg.w);
      *(uint2*)(As + ((buf ^ 1) << 10) + aoff) = aw.v;
      if (kt < 14) {
        areg = *(const float4*)(asrc + (kt + 2) * 32);
        async_cp16(bsrc0 + (kt + 2) * 32, Bs + (buf << 12) + (w << 9));
        async_cp16(bsrc1 + (kt + 2) * 32, Bs + (buf << 12) + ((w + 4) << 9));
        asm volatile("s_waitcnt vmcnt(3)" ::: "memory");
      } else {
        asm volatile("s_waitcnt vmcnt(0)" ::: "memory");
      }
      asm volatile("s_waitcnt lgkmcnt(0)" ::: "memory");
      __builtin_amdgcn_sched_barrier(0);
      __builtin_amdgcn_s_barrier();
    }
    buf ^= 1;
  }
#pragma unroll
  for (int j = 0; j < 4; ++j) {
    const int nn = n0 + wc + j * 16 + lr;
    const float bia = bvb[nn];
    const int mm0 = m0 + wr + lc * 4;
    const int b = mm0 >> 10, t0 = mm0 & 1023;
    const int h = nn >> 6, dk = nn & 63;
    U2 pk;
    pk.u[0] = cvt_pk(acc[j][0] + bia, acc[j][1] + bia);
    pk.u[1] = cvt_pk(acc[j][2] + bia, acc[j][3] + bia);
    *(uint2*)(vt + (((size_t)((b * 8 + h) * 64 + dk)) << 10) + t0) = pk.v;
  }
}

// ---------------- k4: bf16 MFMA GEMM (gemm_o) ----------------
template <int BB16>
__global__ LB void gemm_bt(const unsigned short* __restrict__ A,
                           const void* __restrict__ Bwp,
                           const float* __restrict__ bias, float* __restrict__ outp) {
  __shared__ unsigned short As[2][32 * 32];
  __shared__ unsigned short Bs[2][128 * 32];
  const int tid = threadIdx.x;
  const int w = tid >> 6, l = tid & 63;
  const int lr = l & 15, lc = l >> 4;
  const int bm = blockIdx.x >> 2, bn = blockIdx.x & 3;
  const int m0 = bm * 32, n0 = bn * 128;
  const int wr = (w & 1) * 16, wc = (w >> 1) * 64;
  const int rch = (lc ^ ((lr >> 1) & 3)) << 3;
  const int arow = (w << 3) + (l >> 2);
  const int asc = (l & 3) ^ ((arow >> 1) & 3);
  const unsigned short* asrc = A + (size_t)(m0 + arow) * 512 + (asc << 3);
  const int crow = l >> 2;
  const unsigned short* b16 = (const unsigned short*)Bwp;
  const float* b32 = (const float*)Bwp;
  const int brow0 = (w << 4) + crow, brow1 = ((w + 4) << 4) + crow;
  const unsigned short* bsrc0 = b16 + (size_t)(n0 + brow0) * 512 + (((l & 3) ^ ((brow0 >> 1) & 3)) << 3);
  const unsigned short* bsrc1 = b16 + (size_t)(n0 + brow1) * 512 + (((l & 3) ^ ((brow1 >> 1) & 3)) << 3);

  f32x4 acc[4] = {};
  if (BB16) {
    if (l < 32) async_cp16(asrc, As[0] + (w << 8));
    async_cp16(bsrc0, Bs[0] + (w << 9));
    async_cp16(bsrc1, Bs[0] + ((w + 4) << 9));
    int buf = 0;
    for (int kt = 0; kt < 16; ++kt) {
      if (kt < 15) {
        const int k1 = (kt + 1) * 32;
        if (l < 32) async_cp16(asrc + k1, As[buf ^ 1] + (w << 8));
        async_cp16(bsrc0 + k1, Bs[buf ^ 1] + (w << 9));
        async_cp16(bsrc1 + k1, Bs[buf ^ 1] + ((w + 4) << 9));
        asm volatile("s_waitcnt vmcnt(3)" ::: "memory");
      } else {
        asm volatile("s_waitcnt vmcnt(0)" ::: "memory");
      }
      __builtin_amdgcn_sched_barrier(0);
      __builtin_amdgcn_s_barrier();
      const short8 af = *(const short8*)(As[buf] + (wr + lr) * 32 + rch);
      __builtin_amdgcn_s_setprio(1);
#pragma unroll
      for (int j = 0; j < 4; ++j) {
        const short8 bfr = *(const short8*)(Bs[buf] + (wc + j * 16 + lr) * 32 + rch);
        acc[j] = __builtin_amdgcn_mfma_f32_16x16x32_bf16(af, bfr, acc[j], 0, 0, 0);
      }
      __builtin_amdgcn_s_setprio(0);
      if (kt < 15) __builtin_amdgcn_s_barrier();
      buf ^= 1;
    }
  } else {
    for (int kt = 0; kt < 16; ++kt) {
      const int k0 = kt * 32;
      if (kt) __syncthreads();
      if (l < 32) async_cp16(asrc + k0, As[0] + (w << 8));
#pragma unroll
      for (int it = 0; it < 2; ++it) {
        const int idx = it * 256 + tid;
        const int row = idx >> 2, gr = idx & 3;
        const int sch = (gr ^ ((row >> 1) & 3)) << 3;
        const float4* src = (const float4*)(b32 + (size_t)(n0 + row) * 512 + k0 + gr * 8);
        const float4 b0 = src[0], b1 = src[1];
        U8 t8;
        t8.u[0] = cvt_pk(b0.x, b0.y); t8.u[1] = cvt_pk(b0.z, b0.w);
        t8.u[2] = cvt_pk(b1.x, b1.y); t8.u[3] = cvt_pk(b1.z, b1.w);
        *(uint4*)(Bs[0] + row * 32 + sch) = t8.v;
      }
      __syncthreads();
      const short8 af = *(const short8*)(As[0] + (wr + lr) * 32 + rch);
#pragma unroll
      for (int j = 0; j < 4; ++j) {
        const short8 bfr = *(const short8*)(Bs[0] + (wc + j * 16 + lr) * 32 + rch);
        acc[j] = __builtin_amdgcn_mfma_f32_16x16x32_bf16(af, bfr, acc[j], 0, 0, 0);
      }
    }
  }
#pragma unroll
  for (int j = 0; j < 4; ++j) {
    const int nn = n0 + wc + j * 16 + lr;
    const float bia = bias[nn];
    const int mm0 = m0 + wr + lc * 4;
#pragma unroll
    for (int r = 0; r < 4; ++r)
      outp[(size_t)(mm0 + r) * 512 + nn] = acc[j][r] + bia;
  }
}

// ---------------- k3: fused attention, register-resident V (pinned), proven orientation
// Grid 1024 x 512thr (bh = bid&63 XCD affinity, iblk = bid>>6 -> 64 rows). 8 waves =
// 8 j-eighths (128 j, 4 k-steps). pa built EXACTLY as R12 (proven); V^T fragments
// preloaded to registers and PINNED LIVE via per-dword empty asm (128-bit tied asm
// operands don't compile on gfx950 -- R16 lesson). launch_bounds(512,2) raises the
// VGPR cap so the 16 fragments stay resident (R15 lesson: cap 88 -> sunk loads).
// Main loop: zero LDS staging, zero barriers, zero vmcnt. Serial 8-way combine.
__global__ LB512 void attn_kernel(const float* __restrict__ sq, const float* __restrict__ sk,
                                  const unsigned char* __restrict__ mbits,
                                  const unsigned short* __restrict__ vt,
                                  unsigned short* __restrict__ xb) {
  __shared__ char smem[21504];
  float* sks = (float*)smem;            // [1024] f32 (4KB)
  char* mks = smem + 4096;              // [64 rows][128B], byte-swizzled (8KB)
  // cmb overlays smem after the main loop: [64][81] f32 = 20,736 B
  const int tid = threadIdx.x;
  const int w = tid >> 6, l = tid & 63;
  const int lr = l & 15, lc = l >> 4;
  const int bid = blockIdx.x;
  const int bh = bid & 63, iblk = bid >> 6;
  const int b = bh >> 3, h = bh & 7;
  const int i0b = iblk << 6;   // 64 rows per block
  const int j0 = w << 7;       // 128 j per wave
  const float* sqp = sq + (size_t)bh * 1024;
  const float* skp = sk + (size_t)bh * 1024;
  const unsigned short* vtp = vt + ((size_t)bh << 16);
  const unsigned char* mrow = mbits + ((size_t)b << 17);

  // ---- prologue: stage sks + mks (async), preload V^T frags + sq to registers
  if (w < 4) async_cp16(skp + (w << 8) + l * 4, sks + (w << 8));
  {
    const int row = (w << 3) + (l >> 3);
    const int c = (l & 7) ^ (row & 7);
    async_cp16(mrow + (size_t)(i0b + row) * 128 + (c << 4), mks + (w << 10));
  }
  // B-operand frags: lane holds V^T[dk = c*16 + lr][j = j0 + s*32 + lc*8 .. +7]
  U8 vrb[4][4];
#pragma unroll
  for (int c = 0; c < 4; ++c)
#pragma unroll
    for (int s = 0; s < 4; ++s)
      vrb[c][s].s = *(const short8*)(vtp + (size_t)(c * 16 + lr) * 1024 + j0 + s * 32 + (lc << 3));
  // Pin live per-dword (32-bit tied operands are supported; 128-bit are not).
#pragma unroll
  for (int c = 0; c < 4; ++c)
#pragma unroll
    for (int s = 0; s < 4; ++s)
      asm volatile("" : "+v"(vrb[c][s].u[0]), "+v"(vrb[c][s].u[1]),
                       "+v"(vrb[c][s].u[2]), "+v"(vrb[c][s].u[3]));
  float sq8[4];
#pragma unroll
  for (int t = 0; t < 4; ++t) sq8[t] = sqp[i0b + (t << 4) + lr];
  __syncthreads();

  f32x4 acc[4][4] = {};   // [t: i-tile][c: dk-tile]
  f32x4 accs[4] = {};     // rowsums
  short8 ones;
#pragma unroll
  for (int t = 0; t < 8; ++t) ones[t] = (short)0x3f80;  // bf16 1.0
  const int rx = (lr & 7) << 4;

#pragma unroll
  for (int s = 0; s < 4; ++s) {
    const int jb = j0 + (s << 5);
    const int qb = (jb >> 3) + lc;
    const f32x4 s0 = *(const f32x4*)(sks + jb + (lc << 3));
    const f32x4 s1 = *(const f32x4*)(sks + jb + (lc << 3) + 4);
    U8 pa[4];
#pragma unroll
    for (int t = 0; t < 4; ++t) {
      const int row = (t << 4) + lr;
      const unsigned mb = (unsigned char)mks[(row << 7) + (qb ^ rx)];
      const float sqv = sq8[t];
      float e[8];
#pragma unroll
      for (int u = 0; u < 8; ++u) {
        float sv = sqv + (u < 4 ? s0[u] : s1[u - 4]);
        sv = fmaxf(sv, 0.2f * sv);  // leaky relu (log2e pre-folded)
        const float ex = __builtin_amdgcn_exp2f(sv);
        e[u] = (mb & (1u << u)) ? ex : 0.0f;
      }
      pa[t].u[0] = cvt_pk(e[0], e[1]); pa[t].u[1] = cvt_pk(e[2], e[3]);
      pa[t].u[2] = cvt_pk(e[4], e[5]); pa[t].u[3] = cvt_pk(e[6], e[7]);
    }
    __builtin_amdgcn_s_setprio(1);
#pragma unroll
    for (int c = 0; c < 4; ++c)
#pragma unroll
      for (int t = 0; t < 4; ++t)
        acc[t][c] = __builtin_amdgcn_mfma_f32_16x16x32_bf16(pa[t].s, vrb[c][s].s, acc[t][c], 0, 0, 0);
#pragma unroll
    for (int t = 0; t < 4; ++t)
      accs[t] = __builtin_amdgcn_mfma_f32_16x16x32_bf16(pa[t].s, ones, accs[t], 0, 0, 0);
    __builtin_amdgcn_s_setprio(0);
  }

  // ---- serial 8-way j-combine through one pad-81 buffer (overlays dead sks/mks)
  float* cmb = (float*)smem;  // [64][81] f32
  __syncthreads();
#pragma unroll 1
  for (int src = 1; src < 8; ++src) {
    if (w == src) {
      float* p = cmb + l * 81;
#pragma unroll
      for (int t = 0; t < 4; ++t) {
#pragma unroll
        for (int c = 0; c < 4; ++c) *(f32x4*)(p + (t * 4 + c) * 4) = acc[t][c];
        *(f32x4*)(p + 64 + t * 4) = accs[t];
      }
    }
    __syncthreads();
    if (w == 0) {
      const float* p = cmb + l * 81;
#pragma unroll
      for (int t = 0; t < 4; ++t) {
#pragma unroll
        for (int c = 0; c < 4; ++c) {
          const f32x4 v = *(const f32x4*)(p + (t * 4 + c) * 4);
#pragma unroll
          for (int r = 0; r < 4; ++r) acc[t][c][r] += v[r];
        }
        const f32x4 vs = *(const f32x4*)(p + 64 + t * 4);
#pragma unroll
        for (int r = 0; r < 4; ++r) accs[t][r] += vs[r];
      }
    }
    __syncthreads();
  }
  if (w == 0) {
#pragma unroll
    for (int t = 0; t < 4; ++t) {
#pragma unroll
      for (int r = 0; r < 4; ++r) {
        const float sv = accs[t][r];
        const float inv = sv > 0.0f ? 1.0f / sv : 0.0f;  // fully-masked row -> 0
        const int i = i0b + (t << 4) + (lc << 2) + r;
#pragma unroll
        for (int c = 0; c < 4; ++c)
          xb[(((size_t)(b * 1024 + i)) << 9) + h * 64 + (c << 4) + lr] =
              f2bf(acc[t][c][r] * inv);
      }
    }
  }
}

extern "C" void kernel_launch(void* const* d_in, const int* in_sizes, int n_in,
                              void* d_out, int out_size, void* d_ws, size_t ws_size,
                              hipStream_t stream) {
  const float* query = (const float*)d_in[0];
  const float* key   = (const float*)d_in[1];
  const float* value = (const float*)d_in[2];
  const int*   mask  = (const int*)d_in[3];
  const float* Wq = (const float*)d_in[4];
  const float* bq = (const float*)d_in[5];
  const float* Wk = (const float*)d_in[6];
  const float* bk = (const float*)d_in[7];
  const float* Wv = (const float*)d_in[8];
  const float* bv = (const float*)d_in[9];
  const float* Wo = (const float*)d_in[10];
  const float* bo = (const float*)d_in[11];
  const float* a  = (const float*)d_in[12];

  char* oc = (char*)d_out;
  unsigned short* vt = (unsigned short*)(oc + 0);
  unsigned int* mbits = (unsigned int*)(oc + 8388608);
  float* sqv = (float*)(oc + 9437184);
  float* skv = (float*)(oc + 9699328);
  unsigned short* Bfrag = (unsigned short*)(oc + 9961472);
  float* qkb = (float*)(oc + 9977856);
  unsigned short* wv16 = (unsigned short*)(oc + 10485760);
  unsigned short* xb = (unsigned short*)d_ws;

  const bool roomy = ws_size >= 8912896;
  unsigned short* wo16 = roomy ? (unsigned short*)((char*)d_ws + 8388608) : (unsigned short*)(oc + 11010048);

  prep_kernel<<<528, 256, 0, stream>>>(Wv, Wo, wv16, wo16, Wq, Wk, a, bq, bk, Bfrag, qkb);
  mid_kernel<<<9728, 256, 0, stream>>>(query, key, Bfrag, qkb, sqv, skv,
                                       value, wv16, bv, vt, mask, mbits);
  attn_kernel<<<1024, 512, 0, stream>>>(sqv, skv, (const unsigned char*)mbits, vt, xb);
  if (roomy)
    gemm_bt<1><<<1024, 256, 0, stream>>>(xb, (const void*)wo16, bo, (float*)d_out);
  else
    gemm_bt<0><<<1024, 256, 0, stream>>>(xb, (const void*)Wo, bo, (float*)d_out);
}

// Round 18
// 81.973 us; speedup vs baseline: 1.5383x; 1.5283x over previous
//
#include <hip/hip_runtime.h>
#include <hip/hip_bf16.h>
#include <stdint.h>

// B=8, N=1024, D=512, H=8, DK=64, ALPHA=0.2
//
// Scratch plan:
//   ws : [0..8.4MB) xb (attn out bf16); [8.4..8.9MB) wo16 IF ws_size >= 8,912,896.
//   d_out doubles as scratch (write-before-read, dead before final GEMM):
//     vt    @ 0          8,388,608  (v^T per head: [b][h][dk][n] bf16)
//     mbit  @ 8,388,608  1,048,576  (mask bitset, [b][i][128B])
//     sq    @ 9,437,184    262,144  ([b][h][n] f32, pre-scaled by log2e)
//     sk    @ 9,699,328    262,144
//     Bfrag @ 9,961,472     16,384  (bf16 MFMA B-frags for sqsk)
//     qkb   @ 9,977,856         64
//     wv16  @10,485,760    524,288  (Wv bf16)

typedef __attribute__((ext_vector_type(8))) short short8;
typedef __attribute__((ext_vector_type(4))) float f32x4;

#define LB __launch_bounds__(256)

union U8 { unsigned u[4]; short8 s; uint4 v; };
union U2 { unsigned u[2]; uint2 v; };

__device__ __forceinline__ unsigned short f2bf(float f) {
  unsigned int u = __float_as_uint(f);
  u += 0x7fffu + ((u >> 16) & 1u);
  return (unsigned short)(u >> 16);
}

// v_cvt_pk_bf16_f32: lo16 = bf16(a), hi16 = bf16(b), RNE (bit-identical to f2bf)
__device__ __forceinline__ unsigned cvt_pk(float a, float b) {
  unsigned r;
  asm("v_cvt_pk_bf16_f32 %0, %1, %2" : "=v"(r) : "v"(a), "v"(b));
  return r;
}

// async global->LDS, 16B per lane. lptr = wave-uniform base; gptr = per-lane.
__device__ __forceinline__ void async_cp16(const void* g, void* l) {
  __builtin_amdgcn_global_load_lds(
      (const __attribute__((address_space(1))) unsigned int*)g,
      (__attribute__((address_space(3))) unsigned int*)l, 16, 0, 0);
}

// ---------------- k1: weight casts + fold a into Wq/Wk -> Bfrag ----------------
__global__ LB void prep_kernel(const float* __restrict__ Wv, const float* __restrict__ Wo,
                               unsigned short* __restrict__ wv16, unsigned short* __restrict__ wo16,
                               const float* __restrict__ Wq, const float* __restrict__ Wk,
                               const float* __restrict__ a, const float* __restrict__ bq,
                               const float* __restrict__ bk,
                               unsigned short* __restrict__ Bfrag, float* __restrict__ qkb) {
  const int blk = blockIdx.x, tid = threadIdx.x;
  if (blk < 512) {
    const float* src = blk < 256 ? Wv : Wo;
    unsigned short* dst = blk < 256 ? wv16 : wo16;
    const int idx = ((blk & 255) * 256 + tid) * 4;
    const float4 v = *(const float4*)(src + idx);
    U2 pk;
    pk.u[0] = cvt_pk(v.x, v.y);
    pk.u[1] = cvt_pk(v.z, v.w);
    *(uint2*)(dst + idx) = pk.v;
    return;
  }
  const int t = (blk - 512) * 256 + tid;  // 4096 threads: d fast, h slow
  const int d = t & 511, h = t >> 9;
  float aq = 0.f, ak = 0.f;
#pragma unroll 4
  for (int dk = 0; dk < 64; ++dk) {
    aq += Wq[(size_t)(h * 64 + dk) * 512 + d] * a[h * 128 + dk];
    ak += Wk[(size_t)(h * 64 + dk) * 512 + d] * a[h * 128 + 64 + dk];
  }
  const float L2E = 1.4426950408889634f;
  const int ks = d >> 5, lch = (d >> 3) & 3, tt = d & 7;
  Bfrag[((ks * 64 + (lch << 4) + h) << 3) + tt] = f2bf(aq * L2E);
  Bfrag[((ks * 64 + (lch << 4) + 8 + h) << 3) + tt] = f2bf(ak * L2E);
  if (d == 0) {
    float s1 = 0.f, s2 = 0.f;
    for (int dk = 0; dk < 64; ++dk) {
      s1 += bq[h * 64 + dk] * a[h * 128 + dk];
      s2 += bk[h * 64 + dk] * a[h * 128 + 64 + dk];
    }
    qkb[h] = s1 * L2E;
    qkb[8 + h] = s2 * L2E;
  }
}

// ---------------- k2: gemm_v (0-1023) | sqsk (1024-1535) | maskbits (1536-9727) ------
__global__ LB void mid_kernel(const float* __restrict__ query, const float* __restrict__ key,
                              const unsigned short* __restrict__ Bfrag,
                              const float* __restrict__ qkb,
                              float* __restrict__ sq, float* __restrict__ sk,
                              const float* __restrict__ value,
                              const unsigned short* __restrict__ wv16,
                              const float* __restrict__ bvb, unsigned short* __restrict__ vt,
                              const int* __restrict__ mask, unsigned int* __restrict__ bits) {
  __shared__ char sm[20480];
  const int tid = threadIdx.x, w = tid >> 6, l = tid & 63;
  const int lr = l & 15, lc = l >> 4;
  const int bid = blockIdx.x;
  if (bid >= 1536) {
    // ---------- maskbits: int4 load + nibble pack via LDS ----------
    unsigned char* nb = (unsigned char*)sm;
    const size_t e0 = ((size_t)(bid - 1536) * 256 + tid) * 4;
    const int4 m = *(const int4*)(mask + e0);
    nb[tid] = (unsigned char)((m.x != 0) | ((m.y != 0) << 1) | ((m.z != 0) << 2) | ((m.w != 0) << 3));
    __syncthreads();
    if (tid < 32) {
      const uint2 p = *(const uint2*)(nb + tid * 8);
      const unsigned lo = p.x, hi = p.y;
      const unsigned wl = (lo & 0xFu) | ((lo >> 4) & 0xF0u) | ((lo >> 8) & 0xF00u) | ((lo >> 12) & 0xF000u);
      const unsigned wh = (hi & 0xFu) | ((hi >> 4) & 0xF0u) | ((hi >> 8) & 0xF00u) | ((hi >> 12) & 0xF000u);
      bits[(bid - 1536) * 32 + tid] = wl | (wh << 16);
    }
    return;
  }
  if (bid >= 1024) {
    // ---------- sqsk: rank-16 MFMA skinny GEMM ----------
    float* comb = (float*)sm;
    const int m0 = (bid - 1024) * 16;
    const int k0 = w * 128;
    short8 bf[4];
#pragma unroll
    for (int ks = 0; ks < 4; ++ks)
      bf[ks] = *(const short8*)(Bfrag + (((w * 4 + ks) * 64 + l) << 3));
    const float* qbase = query + (size_t)(m0 + lr) * 512 + k0 + (lc << 3);
    const float* kbase = key + (size_t)(m0 + lr) * 512 + k0 + (lc << 3);
    f32x4 cq = {}, ck = {};
#pragma unroll
    for (int ks = 0; ks < 4; ++ks) {
      const float4 q0 = *(const float4*)(qbase + ks * 32);
      const float4 q1 = *(const float4*)(qbase + ks * 32 + 4);
      const float4 k0v = *(const float4*)(kbase + ks * 32);
      const float4 k1v = *(const float4*)(kbase + ks * 32 + 4);
      U8 aq, ak;
      aq.u[0] = cvt_pk(q0.x, q0.y); aq.u[1] = cvt_pk(q0.z, q0.w);
      aq.u[2] = cvt_pk(q1.x, q1.y); aq.u[3] = cvt_pk(q1.z, q1.w);
      ak.u[0] = cvt_pk(k0v.x, k0v.y); ak.u[1] = cvt_pk(k0v.z, k0v.w);
      ak.u[2] = cvt_pk(k1v.x, k1v.y); ak.u[3] = cvt_pk(k1v.z, k1v.w);
      cq = __builtin_amdgcn_mfma_f32_16x16x32_bf16(aq.s, bf[ks], cq, 0, 0, 0);
      ck = __builtin_amdgcn_mfma_f32_16x16x32_bf16(ak.s, bf[ks], ck, 0, 0, 0);
    }
    if (w) {
      float* p = comb + ((w - 1) * 64 + l) * 9;
#pragma unroll
      for (int r = 0; r < 4; ++r) { p[r] = cq[r]; p[4 + r] = ck[r]; }
    }
    __syncthreads();
    if (w == 0) {
#pragma unroll
      for (int j = 0; j < 3; ++j) {
        const float* p = comb + (j * 64 + l) * 9;
#pragma unroll
        for (int r = 0; r < 4; ++r) { cq[r] += p[r]; ck[r] += p[4 + r]; }
      }
      const int col = l & 15;
      const int mbase = m0 + (lc << 2);
      const int b = mbase >> 10;
      const float bia = qkb[col];
      if (col < 8) {
        float* out = sq + ((size_t)b * 8 + col) * 1024;
#pragma unroll
        for (int r = 0; r < 4; ++r) out[(mbase + r) & 1023] = cq[r] + bia;
      } else {
        float* out = sk + ((size_t)b * 8 + (col - 8)) * 1024;
#pragma unroll
        for (int r = 0; r < 4; ++r) out[(mbase + r) & 1023] = ck[r] + bia;
      }
    }
    return;
  }
  // ---------- gemm_v: vt = value @ Wv^T, A f32 reg-staged, dbuf counted-vmcnt ----------
  unsigned short* As = (unsigned short*)sm;
  unsigned short* Bs = (unsigned short*)(sm + 4096);
  const int bm = bid >> 2, bn = bid & 3;
  const int m0 = bm * 32, n0 = bn * 128;
  const int wr = (w & 1) * 16, wc = (w >> 1) * 64;
  const int rch = (lc ^ ((lr >> 1) & 3)) << 3;
  const int arow = (w << 3) + (l >> 3);
  const int akc = l & 7;
  const float* asrc = value + (size_t)(m0 + arow) * 512 + (akc << 2);
  const int ach = ((akc >> 1) ^ ((arow >> 1) & 3));
  const int aoff = arow * 32 + (ach << 3) + ((akc & 1) << 2);
  const int crow = l >> 2;
  const int brow0 = (w << 4) + crow, brow1 = ((w + 4) << 4) + crow;
  const unsigned short* bsrc0 = wv16 + (size_t)(n0 + brow0) * 512 + (((l & 3) ^ ((brow0 >> 1) & 3)) << 3);
  const unsigned short* bsrc1 = wv16 + (size_t)(n0 + brow1) * 512 + (((l & 3) ^ ((brow1 >> 1) & 3)) << 3);

  f32x4 acc[4] = {};
  float4 areg = *(const float4*)(asrc);
  async_cp16(bsrc0, Bs + (w << 9));
  async_cp16(bsrc1, Bs + ((w + 4) << 9));
  {
    U2 aw;
    aw.u[0] = cvt_pk(areg.x, areg.y);
    aw.u[1] = cvt_pk(areg.z, areg.w);
    *(uint2*)(As + aoff) = aw.v;
  }
  areg = *(const float4*)(asrc + 32);
  async_cp16(bsrc0 + 32, Bs + 4096 + (w << 9));
  async_cp16(bsrc1 + 32, Bs + 4096 + ((w + 4) << 9));
  asm volatile("s_waitcnt vmcnt(3)" ::: "memory");
  asm volatile("s_waitcnt lgkmcnt(0)" ::: "memory");
  __builtin_amdgcn_sched_barrier(0);
  __builtin_amdgcn_s_barrier();
  int buf = 0;
  for (int kt = 0; kt < 16; ++kt) {
    const short8 af = *(const short8*)(As + (buf << 10) + (wr + lr) * 32 + rch);
    __builtin_amdgcn_s_setprio(1);
#pragma unroll
    for (int j = 0; j < 4; ++j) {
      const short8 bfr = *(const short8*)(Bs + (buf << 12) + (wc + j * 16 + lr) * 32 + rch);
      acc[j] = __builtin_amdgcn_mfma_f32_16x16x32_bf16(af, bfr, acc[j], 0, 0, 0);
    }
    __builtin_amdgcn_s_setprio(0);
    __builtin_amdgcn_s_barrier();
    if (kt < 15) {
      U2 aw;
      aw.u[0] = cvt_pk(areg.x, areg.y);
      aw.u[1] = cvt_pk(areg.z, areg.w);
      *(uint2*)(As + ((buf ^ 1) << 10) + aoff) = aw.v;
      if (kt < 14) {
        areg = *(const float4*)(asrc + (kt + 2) * 32);
        async_cp16(bsrc0 + (kt + 2) * 32, Bs + (buf << 12) + (w << 9));
        async_cp16(bsrc1 + (kt + 2) * 32, Bs + (buf << 12) + ((w + 4) << 9));
        asm volatile("s_waitcnt vmcnt(3)" ::: "memory");
      } else {
        asm volatile("s_waitcnt vmcnt(0)" ::: "memory");
      }
      asm volatile("s_waitcnt lgkmcnt(0)" ::: "memory");
      __builtin_amdgcn_sched_barrier(0);
      __builtin_amdgcn_s_barrier();
    }
    buf ^= 1;
  }
#pragma unroll
  for (int j = 0; j < 4; ++j) {
    const int nn = n0 + wc + j * 16 + lr;
    const float bia = bvb[nn];
    const int mm0 = m0 + wr + lc * 4;
    const int b = mm0 >> 10, t0 = mm0 & 1023;
    const int h = nn >> 6, dk = nn & 63;
    U2 pk;
    pk.u[0] = cvt_pk(acc[j][0] + bia, acc[j][1] + bia);
    pk.u[1] = cvt_pk(acc[j][2] + bia, acc[j][3] + bia);
    *(uint2*)(vt + (((size_t)((b * 8 + h) * 64 + dk)) << 10) + t0) = pk.v;
  }
}

// ---------------- k4: bf16 MFMA GEMM (gemm_o) ----------------
template <int BB16>
__global__ LB void gemm_bt(const unsigned short* __restrict__ A,
                           const void* __restrict__ Bwp,
                           const float* __restrict__ bias, float* __restrict__ outp) {
  __shared__ unsigned short As[2][32 * 32];
  __shared__ unsigned short Bs[2][128 * 32];
  const int tid = threadIdx.x;
  const int w = tid >> 6, l = tid & 63;
  const int lr = l & 15, lc = l >> 4;
  const int bm = blockIdx.x >> 2, bn = blockIdx.x & 3;
  const int m0 = bm * 32, n0 = bn * 128;
  const int wr = (w & 1) * 16, wc = (w >> 1) * 64;
  const int rch = (lc ^ ((lr >> 1) & 3)) << 3;
  const int arow = (w << 3) + (l >> 2);
  const int asc = (l & 3) ^ ((arow >> 1) & 3);
  const unsigned short* asrc = A + (size_t)(m0 + arow) * 512 + (asc << 3);
  const int crow = l >> 2;
  const unsigned short* b16 = (const unsigned short*)Bwp;
  const float* b32 = (const float*)Bwp;
  const int brow0 = (w << 4) + crow, brow1 = ((w + 4) << 4) + crow;
  const unsigned short* bsrc0 = b16 + (size_t)(n0 + brow0) * 512 + (((l & 3) ^ ((brow0 >> 1) & 3)) << 3);
  const unsigned short* bsrc1 = b16 + (size_t)(n0 + brow1) * 512 + (((l & 3) ^ ((brow1 >> 1) & 3)) << 3);

  f32x4 acc[4] = {};
  if (BB16) {
    if (l < 32) async_cp16(asrc, As[0] + (w << 8));
    async_cp16(bsrc0, Bs[0] + (w << 9));
    async_cp16(bsrc1, Bs[0] + ((w + 4) << 9));
    int buf = 0;
    for (int kt = 0; kt < 16; ++kt) {
      if (kt < 15) {
        const int k1 = (kt + 1) * 32;
        if (l < 32) async_cp16(asrc + k1, As[buf ^ 1] + (w << 8));
        async_cp16(bsrc0 + k1, Bs[buf ^ 1] + (w << 9));
        async_cp16(bsrc1 + k1, Bs[buf ^ 1] + ((w + 4) << 9));
        asm volatile("s_waitcnt vmcnt(3)" ::: "memory");
      } else {
        asm volatile("s_waitcnt vmcnt(0)" ::: "memory");
      }
      __builtin_amdgcn_sched_barrier(0);
      __builtin_amdgcn_s_barrier();
      const short8 af = *(const short8*)(As[buf] + (wr + lr) * 32 + rch);
      __builtin_amdgcn_s_setprio(1);
#pragma unroll
      for (int j = 0; j < 4; ++j) {
        const short8 bfr = *(const short8*)(Bs[buf] + (wc + j * 16 + lr) * 32 + rch);
        acc[j] = __builtin_amdgcn_mfma_f32_16x16x32_bf16(af, bfr, acc[j], 0, 0, 0);
      }
      __builtin_amdgcn_s_setprio(0);
      if (kt < 15) __builtin_amdgcn_s_barrier();
      buf ^= 1;
    }
  } else {
    for (int kt = 0; kt < 16; ++kt) {
      const int k0 = kt * 32;
      if (kt) __syncthreads();
      if (l < 32) async_cp16(asrc + k0, As[0] + (w << 8));
#pragma unroll
      for (int it = 0; it < 2; ++it) {
        const int idx = it * 256 + tid;
        const int row = idx >> 2, gr = idx & 3;
        const int sch = (gr ^ ((row >> 1) & 3)) << 3;
        const float4* src = (const float4*)(b32 + (size_t)(n0 + row) * 512 + k0 + gr * 8);
        const float4 b0 = src[0], b1 = src[1];
        U8 t8;
        t8.u[0] = cvt_pk(b0.x, b0.y); t8.u[1] = cvt_pk(b0.z, b0.w);
        t8.u[2] = cvt_pk(b1.x, b1.y); t8.u[3] = cvt_pk(b1.z, b1.w);
        *(uint4*)(Bs[0] + row * 32 + sch) = t8.v;
      }
      __syncthreads();
      const short8 af = *(const short8*)(As[0] + (wr + lr) * 32 + rch);
#pragma unroll
      for (int j = 0; j < 4; ++j) {
        const short8 bfr = *(const short8*)(Bs[0] + (wc + j * 16 + lr) * 32 + rch);
        acc[j] = __builtin_amdgcn_mfma_f32_16x16x32_bf16(af, bfr, acc[j], 0, 0, 0);
      }
    }
  }
#pragma unroll
  for (int j = 0; j < 4; ++j) {
    const int nn = n0 + wc + j * 16 + lr;
    const float bia = bias[nn];
    const int mm0 = m0 + wr + lc * 4;
#pragma unroll
    for (int r = 0; r < 4; ++r)
      outp[(size_t)(mm0 + r) * 512 + nn] = acc[j][r] + bia;
  }
}

// ---------------- k3: fused attention = R11 structure + COALESCED V staging ----------
// Grid 512 x 256thr (bh = bid&63 XCD affinity; iblk = bid>>6, 128 rows). 4 waves:
// rh = w&1 (64-row half), jh = w>>1 (512-j half). V slab per jh = [64 dk][64 j] dbuf,
// j-MAJOR coalesced staging (8-lane group = one dk row's 128B, chunk-XOR swizzled;
// 16 full 64B requests/cp vs 64 scattered in R11 -> 8x fewer L2 requests).
// Swizzle: slot q of row dk holds global chunk q ^ f(dk), f(dk)=(dk&7)^(((dk>>3)&1)<<2).
// Pacing: rh-pair co-stages (4 cps each); vmcnt(4) + 2 barriers per 64-j slab.
__global__ LB void attn_kernel(const float* __restrict__ sq, const float* __restrict__ sk,
                               const unsigned char* __restrict__ mbits,
                               const unsigned short* __restrict__ vt,
                               unsigned short* __restrict__ xb) {
  __shared__ char smem[53248];
  unsigned short* vts = (unsigned short*)smem;  // [2 jh][2 buf][64 dk][64 j] = 32KB
  float* sks = (float*)(smem + 32768);          // [1024] f32 (4KB)
  char* mks = smem + 36864;                     // [128 rows][128B], byte-swizzled (16KB)
  const int tid = threadIdx.x;
  const int w = tid >> 6, l = tid & 63;
  const int lr = l & 15, lc = l >> 4;
  const int bid = blockIdx.x;  // 512: bh = bid&63 (XCD: bid%8==h), iblk = bid>>6
  const int bh = bid & 63, iblk = bid >> 6;
  const int b = bh >> 3, h = bh & 7;
  const int i0b = iblk << 7;   // 128 rows per block
  const int rh = w & 1, jh = w >> 1;
  const int j0 = jh << 9;      // 512 j per half
  const float* sqp = sq + (size_t)bh * 1024;
  const float* skp = sk + (size_t)bh * 1024;
  const unsigned short* vtp = vt + ((size_t)bh << 16);
  const unsigned char* mrow = mbits + ((size_t)b << 17);

  // ---- prologue staging (drained by __syncthreads)
  async_cp16(skp + (w << 8) + l * 4, sks + (w << 8));
#pragma unroll
  for (int m = 0; m < 4; ++m) {
    const int row = (w << 5) + (m << 3) + (l >> 3);
    const int c = (l & 7) ^ (row & 7);
    async_cp16(mrow + (size_t)(i0b + row) * 128 + (c << 4), mks + (w << 12) + (m << 10));
  }
  // V staging geometry: wave covers dk [rh*32, rh*32+32) of its jh slab: 4 cps of 8 dk.
  // Lane l: dk_local = l>>3; stored slot chunk = l&7; source chunk = (l&7)^(l>>3)
  // (cp k odd additionally XORs bit2 via f(dk): (dk>>3)&1 == k&1).
  const int sdk = l >> 3;
  const int c0 = (l & 7) ^ sdk;
  const unsigned short* vsA = vtp + (size_t)((rh << 5) + sdk) * 1024 + j0 + (c0 << 3);
  const unsigned short* vsB = vtp + (size_t)((rh << 5) + sdk) * 1024 + j0 + ((c0 ^ 4) << 3);
  unsigned short* vdst = vts + (jh << 13) + ((rh << 5) << 6);  // + buf*4096 + k*512
#define STAGE(bf_, jsl_)                                                       \
  {                                                                            \
    unsigned short* d_ = vdst + ((bf_) << 12);                                 \
    async_cp16(vsA + (jsl_), d_);                                              \
    async_cp16(vsB + 8192 + (jsl_), d_ + 512);                                 \
    async_cp16(vsA + 16384 + (jsl_), d_ + 1024);                               \
    async_cp16(vsB + 24576 + (jsl_), d_ + 1536);                               \
  }
  STAGE(0, 0);
  float sq8[4];
#pragma unroll
  for (int t = 0; t < 4; ++t) sq8[t] = sqp[i0b + (rh << 6) + (t << 4) + lr];
  __syncthreads();

  f32x4 acc[4][4] = {};   // [t: row-tile][c: dk-tile]
  f32x4 accs[4] = {};
  short8 ones;
#pragma unroll
  for (int t = 0; t < 8; ++t) ones[t] = (short)0x3f80;  // bf16 1.0
  const int rx = (lr & 7) << 4;
  const int pxor = (lr & 7) ^ (((lr >> 3) & 1) << 2);  // f(row) for V-frag reads

  int buf = 0;
  for (int slab = 0; slab < 8; ++slab) {
    if (slab < 7) {
      STAGE(buf ^ 1, (slab + 1) << 6);
      asm volatile("s_waitcnt vmcnt(4)" ::: "memory");  // own slab(s) cps landed
    } else {
      asm volatile("s_waitcnt vmcnt(0)" ::: "memory");
    }
    __builtin_amdgcn_sched_barrier(0);
    __builtin_amdgcn_s_barrier();  // partner's cps for slab landed
#pragma unroll
    for (int s2 = 0; s2 < 2; ++s2) {
      const int jb = j0 + (slab << 6) + (s2 << 5);
      const int qb = (jb >> 3) + lc;
      const f32x4 s0 = *(const f32x4*)(sks + jb + (lc << 3));
      const f32x4 s1 = *(const f32x4*)(sks + jb + (lc << 3) + 4);
      U8 pa[4];
#pragma unroll
      for (int t = 0; t < 4; ++t) {
        const int row = (rh << 6) + (t << 4) + lr;
        const unsigned mb = (unsigned char)mks[(row << 7) + (qb ^ rx)];
        const float sqv = sq8[t];
        float e[8];
#pragma unroll
        for (int u = 0; u < 8; ++u) {
          float sv = sqv + (u < 4 ? s0[u] : s1[u - 4]);
          sv = fmaxf(sv, 0.2f * sv);  // leaky relu (log2e pre-folded)
          const float ex = __builtin_amdgcn_exp2f(sv);
          e[u] = (mb & (1u << u)) ? ex : 0.0f;
        }
        pa[t].u[0] = cvt_pk(e[0], e[1]); pa[t].u[1] = cvt_pk(e[2], e[3]);
        pa[t].u[2] = cvt_pk(e[4], e[5]); pa[t].u[3] = cvt_pk(e[6], e[7]);
      }
      const unsigned short* vbb = vts + (jh << 13) + (buf << 12)
                                + ((((s2 << 2) + lc) ^ pxor) << 3);
      __builtin_amdgcn_s_setprio(1);
#pragma unroll
      for (int c = 0; c < 4; ++c) {
        const short8 bv = *(const short8*)(vbb + (((c << 4) + lr) << 6));
#pragma unroll
        for (int t = 0; t < 4; ++t)
          acc[t][c] = __builtin_amdgcn_mfma_f32_16x16x32_bf16(pa[t].s, bv, acc[t][c], 0, 0, 0);
      }
#pragma unroll
      for (int t = 0; t < 4; ++t)
        accs[t] = __builtin_amdgcn_mfma_f32_16x16x32_bf16(pa[t].s, ones, accs[t], 0, 0, 0);
      __builtin_amdgcn_s_setprio(0);
    }
    if (slab < 7) __builtin_amdgcn_s_barrier();  // all done reading buf
    buf ^= 1;
  }
#undef STAGE

  // ---- 2-way jh combine (cmb aliases dead slabs; pad-84)
  __syncthreads();
  float* cmb = (float*)smem;  // [2 rh][64 lane][84] f32 = 43 KB
  if (jh == 1) {
    float* p = cmb + ((rh << 6) + l) * 84;
#pragma unroll
    for (int t = 0; t < 4; ++t) {
#pragma unroll
      for (int c = 0; c < 4; ++c) *(f32x4*)(p + (t * 4 + c) * 4) = acc[t][c];
      *(f32x4*)(p + 64 + t * 4) = accs[t];
    }
  }
  __syncthreads();
  if (jh == 0) {
    const float* p = cmb + ((rh << 6) + l) * 84;
#pragma unroll
    for (int t = 0; t < 4; ++t) {
#pragma unroll
      for (int c = 0; c < 4; ++c) {
        const f32x4 v = *(const f32x4*)(p + (t * 4 + c) * 4);
#pragma unroll
        for (int r = 0; r < 4; ++r) acc[t][c][r] += v[r];
      }
      const f32x4 vs = *(const f32x4*)(p + 64 + t * 4);
#pragma unroll
      for (int r = 0; r < 4; ++r) accs[t][r] += vs[r];
    }
#pragma unroll
    for (int t = 0; t < 4; ++t) {
#pragma unroll
      for (int r = 0; r < 4; ++r) {
        const float sv = accs[t][r];
        const float inv = sv > 0.0f ? 1.0f / sv : 0.0f;  // fully-masked row -> 0
        const int i = i0b + (rh << 6) + (t << 4) + (lc << 2) + r;
#pragma unroll
        for (int c = 0; c < 4; ++c)
          xb[(((size_t)(b * 1024 + i)) << 9) + h * 64 + (c << 4) + lr] =
              f2bf(acc[t][c][r] * inv);
      }
    }
  }
}

extern "C" void kernel_launch(void* const* d_in, const int* in_sizes, int n_in,
                              void* d_out, int out_size, void* d_ws, size_t ws_size,
                              hipStream_t stream) {
  const float* query = (const float*)d_in[0];
  const float* key   = (const float*)d_in[1];
  const float* value = (const float*)d_in[2];
  const int*   mask  = (const int*)d_in[3];
  const float* Wq = (const float*)d_in[4];
  const float* bq = (const float*)d_in[5];
  const float* Wk = (const float*)d_in[6];
  const float* bk = (const float*)d_in[7];
  const float* Wv = (const float*)d_in[8];
  const float* bv = (const float*)d_in[9];
  const float* Wo = (const float*)d_in[10];
  const float* bo = (const float*)d_in[11];
  const float* a  = (const float*)d_in[12];

  char* oc = (char*)d_out;
  unsigned short* vt = (unsigned short*)(oc + 0);
  unsigned int* mbits = (unsigned int*)(oc + 8388608);
  float* sqv = (float*)(oc + 9437184);
  float* skv = (float*)(oc + 9699328);
  unsigned short* Bfrag = (unsigned short*)(oc + 9961472);
  float* qkb = (float*)(oc + 9977856);
  unsigned short* wv16 = (unsigned short*)(oc + 10485760);
  unsigned short* xb = (unsigned short*)d_ws;

  const bool roomy = ws_size >= 8912896;
  unsigned short* wo16 = roomy ? (unsigned short*)((char*)d_ws + 8388608) : (unsigned short*)(oc + 11010048);

  prep_kernel<<<528, 256, 0, stream>>>(Wv, Wo, wv16, wo16, Wq, Wk, a, bq, bk, Bfrag, qkb);
  mid_kernel<<<9728, 256, 0, stream>>>(query, key, Bfrag, qkb, sqv, skv,
                                       value, wv16, bv, vt, mask, mbits);
  attn_kernel<<<512, 256, 0, stream>>>(sqv, skv, (const unsigned char*)mbits, vt, xb);
  if (roomy)
    gemm_bt<1><<<1024, 256, 0, stream>>>(xb, (const void*)wo16, bo, (float*)d_out);
  else
    gemm_bt<0><<<1024, 256, 0, stream>>>(xb, (const void*)Wo, bo, (float*)d_out);
}

// Round 19
// 77.359 us; speedup vs baseline: 1.6300x; 1.0596x over previous
//
#include <hip/hip_runtime.h>
#include <hip/hip_bf16.h>
#include <stdint.h>

// B=8, N=1024, D=512, H=8, DK=64, ALPHA=0.2
//
// Scratch plan:
//   ws : [0..8.4MB) xb (attn out bf16); [8.4..8.9MB) wo16 IF ws_size >= 8,912,896.
//   d_out doubles as scratch (write-before-read, dead before final GEMM):
//     vt    @ 0          8,388,608  (v^T per head: [b][h][dk][n] bf16)
//     mbit  @ 8,388,608  1,048,576  (mask bitset, [b][i][128B])
//     Bfrag @ 9,961,472     16,384  (bf16 MFMA B-frags for sqsk)
//     qkb   @ 9,977,856         64
//     wv16  @10,485,760    524,288  (Wv bf16)
//     sqE   @11,010,048    524,288  (float2[bh][n] = {2^sqL, 2^(0.2 sqL)})
//     skE   @11,534,336    524,288  (float2 pairs for k side)
//     wo16f @12,058,624    524,288  (Wo bf16 fallback dst)

typedef __attribute__((ext_vector_type(8))) short short8;
typedef __attribute__((ext_vector_type(4))) float f32x4;

#define LB __launch_bounds__(256)

union U8 { unsigned u[4]; short8 s; uint4 v; };
union U2 { unsigned u[2]; uint2 v; };

__device__ __forceinline__ unsigned short f2bf(float f) {
  unsigned int u = __float_as_uint(f);
  u += 0x7fffu + ((u >> 16) & 1u);
  return (unsigned short)(u >> 16);
}

// v_cvt_pk_bf16_f32: lo16 = bf16(a), hi16 = bf16(b), RNE (bit-identical to f2bf)
__device__ __forceinline__ unsigned cvt_pk(float a, float b) {
  unsigned r;
  asm("v_cvt_pk_bf16_f32 %0, %1, %2" : "=v"(r) : "v"(a), "v"(b));
  return r;
}

// async global->LDS, 16B per lane. lptr = wave-uniform base; gptr = per-lane.
__device__ __forceinline__ void async_cp16(const void* g, void* l) {
  __builtin_amdgcn_global_load_lds(
      (const __attribute__((address_space(1))) unsigned int*)g,
      (__attribute__((address_space(3))) unsigned int*)l, 16, 0, 0);
}

// ---------------- k1: weight casts + fold a into Wq/Wk -> Bfrag ----------------
__global__ LB void prep_kernel(const float* __restrict__ Wv, const float* __restrict__ Wo,
                               unsigned short* __restrict__ wv16, unsigned short* __restrict__ wo16,
                               const float* __restrict__ Wq, const float* __restrict__ Wk,
                               const float* __restrict__ a, const float* __restrict__ bq,
                               const float* __restrict__ bk,
                               unsigned short* __restrict__ Bfrag, float* __restrict__ qkb) {
  const int blk = blockIdx.x, tid = threadIdx.x;
  if (blk < 512) {
    const float* src = blk < 256 ? Wv : Wo;
    unsigned short* dst = blk < 256 ? wv16 : wo16;
    const int idx = ((blk & 255) * 256 + tid) * 4;
    const float4 v = *(const float4*)(src + idx);
    U2 pk;
    pk.u[0] = cvt_pk(v.x, v.y);
    pk.u[1] = cvt_pk(v.z, v.w);
    *(uint2*)(dst + idx) = pk.v;
    return;
  }
  const int t = (blk - 512) * 256 + tid;  // 4096 threads: d fast, h slow
  const int d = t & 511, h = t >> 9;
  float aq = 0.f, ak = 0.f;
#pragma unroll 4
  for (int dk = 0; dk < 64; ++dk) {
    aq += Wq[(size_t)(h * 64 + dk) * 512 + d] * a[h * 128 + dk];
    ak += Wk[(size_t)(h * 64 + dk) * 512 + d] * a[h * 128 + 64 + dk];
  }
  const float L2E = 1.4426950408889634f;
  const int ks = d >> 5, lch = (d >> 3) & 3, tt = d & 7;
  Bfrag[((ks * 64 + (lch << 4) + h) << 3) + tt] = f2bf(aq * L2E);
  Bfrag[((ks * 64 + (lch << 4) + 8 + h) << 3) + tt] = f2bf(ak * L2E);
  if (d == 0) {
    float s1 = 0.f, s2 = 0.f;
    for (int dk = 0; dk < 64; ++dk) {
      s1 += bq[h * 64 + dk] * a[h * 128 + dk];
      s2 += bk[h * 64 + dk] * a[h * 128 + 64 + dk];
    }
    qkb[h] = s1 * L2E;
    qkb[8 + h] = s2 * L2E;
  }
}

// ---------------- k2: gemm_v (0-1023) | sqsk (1024-1535) | maskbits (1536-9727) ------
// sqsk now emits PRECOMPUTED EXP PAIRS: sqE[n] = {2^v, 2^(0.2v)} (v already L2E-scaled),
// enabling exp-free scores in attn via exp(lrelu(s)) = max(Eq*Ek, eq*ek).
__global__ LB void mid_kernel(const float* __restrict__ query, const float* __restrict__ key,
                              const unsigned short* __restrict__ Bfrag,
                              const float* __restrict__ qkb,
                              float2* __restrict__ sqE, float2* __restrict__ skE,
                              const float* __restrict__ value,
                              const unsigned short* __restrict__ wv16,
                              const float* __restrict__ bvb, unsigned short* __restrict__ vt,
                              const int* __restrict__ mask, unsigned int* __restrict__ bits) {
  __shared__ char sm[20480];
  const int tid = threadIdx.x, w = tid >> 6, l = tid & 63;
  const int lr = l & 15, lc = l >> 4;
  const int bid = blockIdx.x;
  if (bid >= 1536) {
    // ---------- maskbits: int4 load + nibble pack via LDS ----------
    unsigned char* nb = (unsigned char*)sm;
    const size_t e0 = ((size_t)(bid - 1536) * 256 + tid) * 4;
    const int4 m = *(const int4*)(mask + e0);
    nb[tid] = (unsigned char)((m.x != 0) | ((m.y != 0) << 1) | ((m.z != 0) << 2) | ((m.w != 0) << 3));
    __syncthreads();
    if (tid < 32) {
      const uint2 p = *(const uint2*)(nb + tid * 8);
      const unsigned lo = p.x, hi = p.y;
      const unsigned wl = (lo & 0xFu) | ((lo >> 4) & 0xF0u) | ((lo >> 8) & 0xF00u) | ((lo >> 12) & 0xF000u);
      const unsigned wh = (hi & 0xFu) | ((hi >> 4) & 0xF0u) | ((hi >> 8) & 0xF00u) | ((hi >> 12) & 0xF000u);
      bits[(bid - 1536) * 32 + tid] = wl | (wh << 16);
    }
    return;
  }
  if (bid >= 1024) {
    // ---------- sqsk: rank-16 MFMA skinny GEMM -> exp-pair tables ----------
    float* comb = (float*)sm;
    const int m0 = (bid - 1024) * 16;
    const int k0 = w * 128;
    short8 bf[4];
#pragma unroll
    for (int ks = 0; ks < 4; ++ks)
      bf[ks] = *(const short8*)(Bfrag + (((w * 4 + ks) * 64 + l) << 3));
    const float* qbase = query + (size_t)(m0 + lr) * 512 + k0 + (lc << 3);
    const float* kbase = key + (size_t)(m0 + lr) * 512 + k0 + (lc << 3);
    f32x4 cq = {}, ck = {};
#pragma unroll
    for (int ks = 0; ks < 4; ++ks) {
      const float4 q0 = *(const float4*)(qbase + ks * 32);
      const float4 q1 = *(const float4*)(qbase + ks * 32 + 4);
      const float4 k0v = *(const float4*)(kbase + ks * 32);
      const float4 k1v = *(const float4*)(kbase + ks * 32 + 4);
      U8 aq, ak;
      aq.u[0] = cvt_pk(q0.x, q0.y); aq.u[1] = cvt_pk(q0.z, q0.w);
      aq.u[2] = cvt_pk(q1.x, q1.y); aq.u[3] = cvt_pk(q1.z, q1.w);
      ak.u[0] = cvt_pk(k0v.x, k0v.y); ak.u[1] = cvt_pk(k0v.z, k0v.w);
      ak.u[2] = cvt_pk(k1v.x, k1v.y); ak.u[3] = cvt_pk(k1v.z, k1v.w);
      cq = __builtin_amdgcn_mfma_f32_16x16x32_bf16(aq.s, bf[ks], cq, 0, 0, 0);
      ck = __builtin_amdgcn_mfma_f32_16x16x32_bf16(ak.s, bf[ks], ck, 0, 0, 0);
    }
    if (w) {
      float* p = comb + ((w - 1) * 64 + l) * 9;
#pragma unroll
      for (int r = 0; r < 4; ++r) { p[r] = cq[r]; p[4 + r] = ck[r]; }
    }
    __syncthreads();
    if (w == 0) {
#pragma unroll
      for (int j = 0; j < 3; ++j) {
        const float* p = comb + (j * 64 + l) * 9;
#pragma unroll
        for (int r = 0; r < 4; ++r) { cq[r] += p[r]; ck[r] += p[4 + r]; }
      }
      const int col = l & 15;
      const int mbase = m0 + (lc << 2);
      const int b = mbase >> 10;
      const float bia = qkb[col];
      if (col < 8) {
        float2* out = sqE + ((size_t)b * 8 + col) * 1024;
#pragma unroll
        for (int r = 0; r < 4; ++r) {
          const float v = cq[r] + bia;
          float2 pr;
          pr.x = __builtin_amdgcn_exp2f(v);
          pr.y = __builtin_amdgcn_exp2f(0.2f * v);
          out[(mbase + r) & 1023] = pr;
        }
      } else {
        float2* out = skE + ((size_t)b * 8 + (col - 8)) * 1024;
#pragma unroll
        for (int r = 0; r < 4; ++r) {
          const float v = ck[r] + bia;
          float2 pr;
          pr.x = __builtin_amdgcn_exp2f(v);
          pr.y = __builtin_amdgcn_exp2f(0.2f * v);
          out[(mbase + r) & 1023] = pr;
        }
      }
    }
    return;
  }
  // ---------- gemm_v: vt = value @ Wv^T, A f32 reg-staged, dbuf counted-vmcnt ----------
  unsigned short* As = (unsigned short*)sm;
  unsigned short* Bs = (unsigned short*)(sm + 4096);
  const int bm = bid >> 2, bn = bid & 3;
  const int m0 = bm * 32, n0 = bn * 128;
  const int wr = (w & 1) * 16, wc = (w >> 1) * 64;
  const int rch = (lc ^ ((lr >> 1) & 3)) << 3;
  const int arow = (w << 3) + (l >> 3);
  const int akc = l & 7;
  const float* asrc = value + (size_t)(m0 + arow) * 512 + (akc << 2);
  const int ach = ((akc >> 1) ^ ((arow >> 1) & 3));
  const int aoff = arow * 32 + (ach << 3) + ((akc & 1) << 2);
  const int crow = l >> 2;
  const int brow0 = (w << 4) + crow, brow1 = ((w + 4) << 4) + crow;
  const unsigned short* bsrc0 = wv16 + (size_t)(n0 + brow0) * 512 + (((l & 3) ^ ((brow0 >> 1) & 3)) << 3);
  const unsigned short* bsrc1 = wv16 + (size_t)(n0 + brow1) * 512 + (((l & 3) ^ ((brow1 >> 1) & 3)) << 3);

  f32x4 acc[4] = {};
  float4 areg = *(const float4*)(asrc);
  async_cp16(bsrc0, Bs + (w << 9));
  async_cp16(bsrc1, Bs + ((w + 4) << 9));
  {
    U2 aw;
    aw.u[0] = cvt_pk(areg.x, areg.y);
    aw.u[1] = cvt_pk(areg.z, areg.w);
    *(uint2*)(As + aoff) = aw.v;
  }
  areg = *(const float4*)(asrc + 32);
  async_cp16(bsrc0 + 32, Bs + 4096 + (w << 9));
  async_cp16(bsrc1 + 32, Bs + 4096 + ((w + 4) << 9));
  asm volatile("s_waitcnt vmcnt(3)" ::: "memory");
  asm volatile("s_waitcnt lgkmcnt(0)" ::: "memory");
  __builtin_amdgcn_sched_barrier(0);
  __builtin_amdgcn_s_barrier();
  int buf = 0;
  for (int kt = 0; kt < 16; ++kt) {
    const short8 af = *(const short8*)(As + (buf << 10) + (wr + lr) * 32 + rch);
    __builtin_amdgcn_s_setprio(1);
#pragma unroll
    for (int j = 0; j < 4; ++j) {
      const short8 bfr = *(const short8*)(Bs + (buf << 12) + (wc + j * 16 + lr) * 32 + rch);
      acc[j] = __builtin_amdgcn_mfma_f32_16x16x32_bf16(af, bfr, acc[j], 0, 0, 0);
    }
    __builtin_amdgcn_s_setprio(0);
    __builtin_amdgcn_s_barrier();
    if (kt < 15) {
      U2 aw;
      aw.u[0] = cvt_pk(areg.x, areg.y);
      aw.u[1] = cvt_pk(areg.z, areg.w);
      *(uint2*)(As + ((buf ^ 1) << 10) + aoff) = aw.v;
      if (kt < 14) {
        areg = *(const float4*)(asrc + (kt + 2) * 32);
        async_cp16(bsrc0 + (kt + 2) * 32, Bs + (buf << 12) + (w << 9));
        async_cp16(bsrc1 + (kt + 2) * 32, Bs + (buf << 12) + ((w + 4) << 9));
        asm volatile("s_waitcnt vmcnt(3)" ::: "memory");
      } else {
        asm volatile("s_waitcnt vmcnt(0)" ::: "memory");
      }
      asm volatile("s_waitcnt lgkmcnt(0)" ::: "memory");
      __builtin_amdgcn_sched_barrier(0);
      __builtin_amdgcn_s_barrier();
    }
    buf ^= 1;
  }
#pragma unroll
  for (int j = 0; j < 4; ++j) {
    const int nn = n0 + wc + j * 16 + lr;
    const float bia = bvb[nn];
    const int mm0 = m0 + wr + lc * 4;
    const int b = mm0 >> 10, t0 = mm0 & 1023;
    const int h = nn >> 6, dk = nn & 63;
    U2 pk;
    pk.u[0] = cvt_pk(acc[j][0] + bia, acc[j][1] + bia);
    pk.u[1] = cvt_pk(acc[j][2] + bia, acc[j][3] + bia);
    *(uint2*)(vt + (((size_t)((b * 8 + h) * 64 + dk)) << 10) + t0) = pk.v;
  }
}

// ---------------- k4: bf16 MFMA GEMM (gemm_o) ----------------
template <int BB16>
__global__ LB void gemm_bt(const unsigned short* __restrict__ A,
                           const void* __restrict__ Bwp,
                           const float* __restrict__ bias, float* __restrict__ outp) {
  __shared__ unsigned short As[2][32 * 32];
  __shared__ unsigned short Bs[2][128 * 32];
  const int tid = threadIdx.x;
  const int w = tid >> 6, l = tid & 63;
  const int lr = l & 15, lc = l >> 4;
  const int bm = blockIdx.x >> 2, bn = blockIdx.x & 3;
  const int m0 = bm * 32, n0 = bn * 128;
  const int wr = (w & 1) * 16, wc = (w >> 1) * 64;
  const int rch = (lc ^ ((lr >> 1) & 3)) << 3;
  const int arow = (w << 3) + (l >> 2);
  const int asc = (l & 3) ^ ((arow >> 1) & 3);
  const unsigned short* asrc = A + (size_t)(m0 + arow) * 512 + (asc << 3);
  const int crow = l >> 2;
  const unsigned short* b16 = (const unsigned short*)Bwp;
  const float* b32 = (const float*)Bwp;
  const int brow0 = (w << 4) + crow, brow1 = ((w + 4) << 4) + crow;
  const unsigned short* bsrc0 = b16 + (size_t)(n0 + brow0) * 512 + (((l & 3) ^ ((brow0 >> 1) & 3)) << 3);
  const unsigned short* bsrc1 = b16 + (size_t)(n0 + brow1) * 512 + (((l & 3) ^ ((brow1 >> 1) & 3)) << 3);

  f32x4 acc[4] = {};
  if (BB16) {
    if (l < 32) async_cp16(asrc, As[0] + (w << 8));
    async_cp16(bsrc0, Bs[0] + (w << 9));
    async_cp16(bsrc1, Bs[0] + ((w + 4) << 9));
    int buf = 0;
    for (int kt = 0; kt < 16; ++kt) {
      if (kt < 15) {
        const int k1 = (kt + 1) * 32;
        if (l < 32) async_cp16(asrc + k1, As[buf ^ 1] + (w << 8));
        async_cp16(bsrc0 + k1, Bs[buf ^ 1] + (w << 9));
        async_cp16(bsrc1 + k1, Bs[buf ^ 1] + ((w + 4) << 9));
        asm volatile("s_waitcnt vmcnt(3)" ::: "memory");
      } else {
        asm volatile("s_waitcnt vmcnt(0)" ::: "memory");
      }
      __builtin_amdgcn_sched_barrier(0);
      __builtin_amdgcn_s_barrier();
      const short8 af = *(const short8*)(As[buf] + (wr + lr) * 32 + rch);
      __builtin_amdgcn_s_setprio(1);
#pragma unroll
      for (int j = 0; j < 4; ++j) {
        const short8 bfr = *(const short8*)(Bs[buf] + (wc + j * 16 + lr) * 32 + rch);
        acc[j] = __builtin_amdgcn_mfma_f32_16x16x32_bf16(af, bfr, acc[j], 0, 0, 0);
      }
      __builtin_amdgcn_s_setprio(0);
      if (kt < 15) __builtin_amdgcn_s_barrier();
      buf ^= 1;
    }
  } else {
    for (int kt = 0; kt < 16; ++kt) {
      const int k0 = kt * 32;
      if (kt) __syncthreads();
      if (l < 32) async_cp16(asrc + k0, As[0] + (w << 8));
#pragma unroll
      for (int it = 0; it < 2; ++it) {
        const int idx = it * 256 + tid;
        const int row = idx >> 2, gr = idx & 3;
        const int sch = (gr ^ ((row >> 1) & 3)) << 3;
        const float4* src = (const float4*)(b32 + (size_t)(n0 + row) * 512 + k0 + gr * 8);
        const float4 b0 = src[0], b1 = src[1];
        U8 t8;
        t8.u[0] = cvt_pk(b0.x, b0.y); t8.u[1] = cvt_pk(b0.z, b0.w);
        t8.u[2] = cvt_pk(b1.x, b1.y); t8.u[3] = cvt_pk(b1.z, b1.w);
        *(uint4*)(Bs[0] + row * 32 + sch) = t8.v;
      }
      __syncthreads();
      const short8 af = *(const short8*)(As[0] + (wr + lr) * 32 + rch);
#pragma unroll
      for (int j = 0; j < 4; ++j) {
        const short8 bfr = *(const short8*)(Bs[0] + (wc + j * 16 + lr) * 32 + rch);
        acc[j] = __builtin_amdgcn_mfma_f32_16x16x32_bf16(af, bfr, acc[j], 0, 0, 0);
      }
    }
  }
#pragma unroll
  for (int j = 0; j < 4; ++j) {
    const int nn = n0 + wc + j * 16 + lr;
    const float bia = bias[nn];
    const int mm0 = m0 + wr + lc * 4;
#pragma unroll
    for (int r = 0; r < 4; ++r)
      outp[(size_t)(mm0 + r) * 512 + nn] = acc[j][r] + bia;
  }
}

// ---------------- k3: fused attention, EXP-FREE scores (R18 structure) ----------------
// exp(lrelu(sq+sk)) = max(Eq*Ek, eq*ek) with precomputed pairs -> no transcendentals
// in the main loop. Everything else identical to R18 (proven): grid 512 x 256thr,
// rh/jh wave split, coalesced dbuf V staging, vmcnt(4)+barrier pacing, 2-way combine.
__global__ LB void attn_kernel(const float2* __restrict__ sqE, const float2* __restrict__ skE,
                               const unsigned char* __restrict__ mbits,
                               const unsigned short* __restrict__ vt,
                               unsigned short* __restrict__ xb) {
  __shared__ char smem[57344];
  unsigned short* vts = (unsigned short*)smem;  // [2 jh][2 buf][64 dk][64 j] = 32KB
  float* sksE = (float*)(smem + 32768);         // [1024 float2] = 8KB
  char* mks = smem + 40960;                     // [128 rows][128B], byte-swizzled (16KB)
  const int tid = threadIdx.x;
  const int w = tid >> 6, l = tid & 63;
  const int lr = l & 15, lc = l >> 4;
  const int bid = blockIdx.x;  // 512: bh = bid&63 (XCD: bid%8==h), iblk = bid>>6
  const int bh = bid & 63, iblk = bid >> 6;
  const int b = bh >> 3, h = bh & 7;
  const int i0b = iblk << 7;   // 128 rows per block
  const int rh = w & 1, jh = w >> 1;
  const int j0 = jh << 9;      // 512 j per half
  const float* sqEp = (const float*)(sqE + (size_t)bh * 1024);
  const float* skEp = (const float*)(skE + (size_t)bh * 1024);
  const unsigned short* vtp = vt + ((size_t)bh << 16);
  const unsigned char* mrow = mbits + ((size_t)b << 17);

  // ---- prologue staging (drained by __syncthreads)
  async_cp16(skEp + (w << 9) + l * 4, sksE + (w << 9));
  async_cp16(skEp + (w << 9) + 256 + l * 4, sksE + (w << 9) + 256);
#pragma unroll
  for (int m = 0; m < 4; ++m) {
    const int row = (w << 5) + (m << 3) + (l >> 3);
    const int c = (l & 7) ^ (row & 7);
    async_cp16(mrow + (size_t)(i0b + row) * 128 + (c << 4), mks + (w << 12) + (m << 10));
  }
  // V staging (R18 geometry)
  const int sdk = l >> 3;
  const int c0 = (l & 7) ^ sdk;
  const unsigned short* vsA = vtp + (size_t)((rh << 5) + sdk) * 1024 + j0 + (c0 << 3);
  const unsigned short* vsB = vtp + (size_t)((rh << 5) + sdk) * 1024 + j0 + ((c0 ^ 4) << 3);
  unsigned short* vdst = vts + (jh << 13) + ((rh << 5) << 6);
#define STAGE(bf_, jsl_)                                                       \
  {                                                                            \
    unsigned short* d_ = vdst + ((bf_) << 12);                                 \
    async_cp16(vsA + (jsl_), d_);                                              \
    async_cp16(vsB + 8192 + (jsl_), d_ + 512);                                 \
    async_cp16(vsA + 16384 + (jsl_), d_ + 1024);                               \
    async_cp16(vsB + 24576 + (jsl_), d_ + 1536);                               \
  }
  STAGE(0, 0);
  float2 E8[4];
#pragma unroll
  for (int t = 0; t < 4; ++t)
    E8[t] = *(const float2*)(sqEp + ((i0b + (rh << 6) + (t << 4) + lr) << 1));
  __syncthreads();

  f32x4 acc[4][4] = {};   // [t: row-tile][c: dk-tile]
  f32x4 accs[4] = {};
  short8 ones;
#pragma unroll
  for (int t = 0; t < 8; ++t) ones[t] = (short)0x3f80;  // bf16 1.0
  const int rx = (lr & 7) << 4;
  const int pxor = (lr & 7) ^ (((lr >> 3) & 1) << 2);  // f(row) for V-frag reads

  int buf = 0;
  for (int slab = 0; slab < 8; ++slab) {
    if (slab < 7) {
      STAGE(buf ^ 1, (slab + 1) << 6);
      asm volatile("s_waitcnt vmcnt(4)" ::: "memory");
    } else {
      asm volatile("s_waitcnt vmcnt(0)" ::: "memory");
    }
    __builtin_amdgcn_sched_barrier(0);
    __builtin_amdgcn_s_barrier();
#pragma unroll
    for (int s2 = 0; s2 < 2; ++s2) {
      const int jb = j0 + (slab << 6) + (s2 << 5);
      const int qb = (jb >> 3) + lc;
      const float* sp = sksE + ((jb + (lc << 3)) << 1);  // 8 (Ek,ek) pairs
      const f32x4 q0 = *(const f32x4*)(sp);
      const f32x4 q1 = *(const f32x4*)(sp + 4);
      const f32x4 q2 = *(const f32x4*)(sp + 8);
      const f32x4 q3 = *(const f32x4*)(sp + 12);
      U8 pa[4];
#pragma unroll
      for (int t = 0; t < 4; ++t) {
        const int row = (rh << 6) + (t << 4) + lr;
        const unsigned mb = (unsigned char)mks[(row << 7) + (qb ^ rx)];
        const float Eq = E8[t].x, eq = E8[t].y;
        float e[8];
        e[0] = fmaxf(Eq * q0[0], eq * q0[1]); e[1] = fmaxf(Eq * q0[2], eq * q0[3]);
        e[2] = fmaxf(Eq * q1[0], eq * q1[1]); e[3] = fmaxf(Eq * q1[2], eq * q1[3]);
        e[4] = fmaxf(Eq * q2[0], eq * q2[1]); e[5] = fmaxf(Eq * q2[2], eq * q2[3]);
        e[6] = fmaxf(Eq * q3[0], eq * q3[1]); e[7] = fmaxf(Eq * q3[2], eq * q3[3]);
#pragma unroll
        for (int u = 0; u < 8; ++u)
          e[u] = (mb & (1u << u)) ? e[u] : 0.0f;
        pa[t].u[0] = cvt_pk(e[0], e[1]); pa[t].u[1] = cvt_pk(e[2], e[3]);
        pa[t].u[2] = cvt_pk(e[4], e[5]); pa[t].u[3] = cvt_pk(e[6], e[7]);
      }
      const unsigned short* vbb = vts + (jh << 13) + (buf << 12)
                                + ((((s2 << 2) + lc) ^ pxor) << 3);
      __builtin_amdgcn_s_setprio(1);
#pragma unroll
      for (int c = 0; c < 4; ++c) {
        const short8 bv = *(const short8*)(vbb + (((c << 4) + lr) << 6));
#pragma unroll
        for (int t = 0; t < 4; ++t)
          acc[t][c] = __builtin_amdgcn_mfma_f32_16x16x32_bf16(pa[t].s, bv, acc[t][c], 0, 0, 0);
      }
#pragma unroll
      for (int t = 0; t < 4; ++t)
        accs[t] = __builtin_amdgcn_mfma_f32_16x16x32_bf16(pa[t].s, ones, accs[t], 0, 0, 0);
      __builtin_amdgcn_s_setprio(0);
    }
    if (slab < 7) __builtin_amdgcn_s_barrier();
    buf ^= 1;
  }
#undef STAGE

  // ---- 2-way jh combine (cmb aliases dead slabs; pad-84)
  __syncthreads();
  float* cmb = (float*)smem;  // [2 rh][64 lane][84] f32 = 43 KB
  if (jh == 1) {
    float* p = cmb + ((rh << 6) + l) * 84;
#pragma unroll
    for (int t = 0; t < 4; ++t) {
#pragma unroll
      for (int c = 0; c < 4; ++c) *(f32x4*)(p + (t * 4 + c) * 4) = acc[t][c];
      *(f32x4*)(p + 64 + t * 4) = accs[t];
    }
  }
  __syncthreads();
  if (jh == 0) {
    const float* p = cmb + ((rh << 6) + l) * 84;
#pragma unroll
    for (int t = 0; t < 4; ++t) {
#pragma unroll
      for (int c = 0; c < 4; ++c) {
        const f32x4 v = *(const f32x4*)(p + (t * 4 + c) * 4);
#pragma unroll
        for (int r = 0; r < 4; ++r) acc[t][c][r] += v[r];
      }
      const f32x4 vs = *(const f32x4*)(p + 64 + t * 4);
#pragma unroll
      for (int r = 0; r < 4; ++r) accs[t][r] += vs[r];
    }
#pragma unroll
    for (int t = 0; t < 4; ++t) {
#pragma unroll
      for (int r = 0; r < 4; ++r) {
        const float sv = accs[t][r];
        const float inv = sv > 0.0f ? 1.0f / sv : 0.0f;  // fully-masked row -> 0
        const int i = i0b + (rh << 6) + (t << 4) + (lc << 2) + r;
#pragma unroll
        for (int c = 0; c < 4; ++c)
          xb[(((size_t)(b * 1024 + i)) << 9) + h * 64 + (c << 4) + lr] =
              f2bf(acc[t][c][r] * inv);
      }
    }
  }
}

extern "C" void kernel_launch(void* const* d_in, const int* in_sizes, int n_in,
                              void* d_out, int out_size, void* d_ws, size_t ws_size,
                              hipStream_t stream) {
  const float* query = (const float*)d_in[0];
  const float* key   = (const float*)d_in[1];
  const float* value = (const float*)d_in[2];
  const int*   mask  = (const int*)d_in[3];
  const float* Wq = (const float*)d_in[4];
  const float* bq = (const float*)d_in[5];
  const float* Wk = (const float*)d_in[6];
  const float* bk = (const float*)d_in[7];
  const float* Wv = (const float*)d_in[8];
  const float* bv = (const float*)d_in[9];
  const float* Wo = (const float*)d_in[10];
  const float* bo = (const float*)d_in[11];
  const float* a  = (const float*)d_in[12];

  char* oc = (char*)d_out;
  unsigned short* vt = (unsigned short*)(oc + 0);
  unsigned int* mbits = (unsigned int*)(oc + 8388608);
  unsigned short* Bfrag = (unsigned short*)(oc + 9961472);
  float* qkb = (float*)(oc + 9977856);
  unsigned short* wv16 = (unsigned short*)(oc + 10485760);
  float2* sqE = (float2*)(oc + 11010048);
  float2* skE = (float2*)(oc + 11534336);
  unsigned short* wo16f = (unsigned short*)(oc + 12058624);
  unsigned short* xb = (unsigned short*)d_ws;

  const bool roomy = ws_size >= 8912896;
  unsigned short* wo16 = roomy ? (unsigned short*)((char*)d_ws + 8388608) : wo16f;

  prep_kernel<<<528, 256, 0, stream>>>(Wv, Wo, wv16, wo16, Wq, Wk, a, bq, bk, Bfrag, qkb);
  mid_kernel<<<9728, 256, 0, stream>>>(query, key, Bfrag, qkb, sqE, skE,
                                       value, wv16, bv, vt, mask, mbits);
  attn_kernel<<<512, 256, 0, stream>>>(sqE, skE, (const unsigned char*)mbits, vt, xb);
  if (roomy)
    gemm_bt<1><<<1024, 256, 0, stream>>>(xb, (const void*)wo16, bo, (float*)d_out);
  else
    gemm_bt<0><<<1024, 256, 0, stream>>>(xb, (const void*)Wo, bo, (float*)d_out);
}